// Round 1
// baseline (2526.668 us; speedup 1.0000x reference)
//
#include <hip/hip_runtime.h>

#define T_ 2048
#define HID_ 2048
#define H_ 16
#define KV_ 8
#define G_ 2
#define D_ 128
#define GH_ 128
#define BS_ 64
#define NB_ 32
#define START_ 409
#define SCALE_ 0.08838834764831845f  // 1/sqrt(128), also 1/sqrt(GH)

// ---------- helpers ----------
__device__ __forceinline__ float wave_sum(float v) {
#pragma unroll
  for (int o = 32; o > 0; o >>= 1) v += __shfl_xor(v, o, 64);
  return v;
}
__device__ __forceinline__ float wave_max(float v) {
#pragma unroll
  for (int o = 32; o > 0; o >>= 1) v = fmaxf(v, __shfl_xor(v, o, 64));
  return v;
}
__device__ __forceinline__ unsigned short f2bf(float x) {
  unsigned int u = __float_as_uint(x);
  unsigned int r = (u + 0x7fffu + ((u >> 16) & 1u)) >> 16;
  return (unsigned short)r;
}
__device__ __forceinline__ float bf2f(unsigned short h) {
  return __uint_as_float(((unsigned int)h) << 16);
}

// ---------- generic fp32 GEMM: C = A(MxK) @ B(KxN); M%64==0, N%64==0, K%16==0 ----------
__global__ __launch_bounds__(256) void gemm_kernel(const float* __restrict__ A,
                                                   const float* __restrict__ B,
                                                   float* __restrict__ C,
                                                   int M, int N, int K) {
  __shared__ float Ast[16][68];  // [k][m], padded: store-bank-conflict-free
  __shared__ float Bs[16][64];
  int tid = threadIdx.x;
  int tx = tid & 15, ty = tid >> 4;
  int m0 = blockIdx.y * 64, n0 = blockIdx.x * 64;
  float acc[4][4] = {};
  for (int k0 = 0; k0 < K; k0 += 16) {
#pragma unroll
    for (int r = 0; r < 4; ++r) {
      int e = tid + 256 * r;
      int m = e >> 4, kk = e & 15;
      Ast[kk][m] = A[(size_t)(m0 + m) * K + k0 + kk];
    }
#pragma unroll
    for (int r = 0; r < 4; ++r) {
      int e = tid + 256 * r;
      int kk = e >> 6, n = e & 63;
      Bs[kk][n] = B[(size_t)(k0 + kk) * N + n0 + n];
    }
    __syncthreads();
#pragma unroll
    for (int kk = 0; kk < 16; ++kk) {
      float4 a4 = *(const float4*)&Ast[kk][ty * 4];
      float4 b4 = *(const float4*)&Bs[kk][tx * 4];
      float av[4] = {a4.x, a4.y, a4.z, a4.w};
      float bv[4] = {b4.x, b4.y, b4.z, b4.w};
#pragma unroll
      for (int i = 0; i < 4; ++i)
#pragma unroll
        for (int j = 0; j < 4; ++j) acc[i][j] += av[i] * bv[j];
    }
    __syncthreads();
  }
#pragma unroll
  for (int i = 0; i < 4; ++i)
#pragma unroll
    for (int j = 0; j < 4; ++j)
      C[(size_t)(m0 + ty * 4 + i) * N + n0 + tx * 4 + j] = acc[i][j];
}

// ---------- q: rmsnorm + pool(mean over G heads, pre-rope) + rope (in place) ----------
__global__ __launch_bounds__(128) void qnorm_rope_pool(float* q, const float* __restrict__ w,
                                                       const float* __restrict__ cosT,
                                                       const float* __restrict__ sinT,
                                                       float* __restrict__ qpool) {
  int t = blockIdx.x, kv = blockIdx.y, d = threadIdx.x;
  int i0 = ((t * H_) + kv * G_) * D_ + d;
  int i1 = i0 + D_;
  float x0 = q[i0], x1 = q[i1];
  __shared__ float sred[2][2];
  float s0 = wave_sum(x0 * x0), s1 = wave_sum(x1 * x1);
  if ((d & 63) == 0) { sred[0][d >> 6] = s0; sred[1][d >> 6] = s1; }
  __syncthreads();
  float wv = w[d];
  float n0 = x0 * rsqrtf((sred[0][0] + sred[0][1]) * (1.f / D_) + 1e-6f) * wv;
  float n1 = x1 * rsqrtf((sred[1][0] + sred[1][1]) * (1.f / D_) + 1e-6f) * wv;
  qpool[(t * KV_ + kv) * D_ + d] = 0.5f * (n0 + n1);
  __shared__ float sh[2][D_];
  sh[0][d] = n0; sh[1][d] = n1;
  __syncthreads();
  float c = cosT[t * D_ + d], s = sinT[t * D_ + d];
  float r0 = (d < 64) ? -sh[0][d + 64] : sh[0][d - 64];
  float r1 = (d < 64) ? -sh[1][d + 64] : sh[1][d - 64];
  q[i0] = n0 * c + r0 * s;
  q[i1] = n1 * c + r1 * s;
}

// ---------- k: rmsnorm (store pre-rope to knorm) + rope (in place) ----------
__global__ __launch_bounds__(128) void knorm_rope(float* k, const float* __restrict__ w,
                                                  const float* __restrict__ cosT,
                                                  const float* __restrict__ sinT,
                                                  float* __restrict__ knorm) {
  int t = blockIdx.x, kv = blockIdx.y, d = threadIdx.x;
  int idx = (t * KV_ + kv) * D_ + d;
  float x = k[idx];
  __shared__ float sred[2];
  float s0 = wave_sum(x * x);
  if ((d & 63) == 0) sred[d >> 6] = s0;
  __syncthreads();
  float nk = x * rsqrtf((sred[0] + sred[1]) * (1.f / D_) + 1e-6f) * w[d];
  knorm[idx] = nk;
  __shared__ float sh[D_];
  sh[d] = nk;
  __syncthreads();
  float rot = (d < 64) ? -sh[d + 64] : sh[d - 64];
  k[idx] = nk * cosT[t * D_ + d] + rot * sinT[t * D_ + d];
}

// ---------- k_blk = mean over BS rows of knorm ----------
__global__ __launch_bounds__(128) void kblk_kernel(const float* __restrict__ knorm,
                                                   float* __restrict__ kblk) {
  int n = blockIdx.x, kv = blockIdx.y, d = threadIdx.x;
  float s = 0.f;
  for (int i = 0; i < BS_; ++i) s += knorm[((n * BS_ + i) * KV_ + kv) * D_ + d];
  kblk[(n * KV_ + kv) * D_ + d] = s * (1.f / BS_);
}

// ---------- generic rope over (rows, KV, GH), table indexed by row ----------
__global__ __launch_bounds__(128) void rope_g_kernel(float* x, const float* __restrict__ cs,
                                                     const float* __restrict__ sn) {
  int r = blockIdx.x, kv = blockIdx.y, d = threadIdx.x;
  int base = (r * KV_ + kv) * GH_;
  __shared__ float sh[GH_];
  sh[d] = x[base + d];
  __syncthreads();
  float rot = (d < 64) ? -sh[d + 64] : sh[d - 64];
  x[base + d] = sh[d] * cs[r * GH_ + d] + rot * sn[r * GH_ + d];
}

// ---------- flash attention; 4 waves/block, 1 query row per wave; chunk = key block (64) ----------
// also accumulates pooled[h][t][n] = sum of probs over key block n
__global__ __launch_bounds__(256) void attn_kernel(const float* __restrict__ qr,
                                                   const float* __restrict__ kr,
                                                   const float* __restrict__ vv,
                                                   float* __restrict__ attnb,
                                                   float* __restrict__ pooled) {
  int h = blockIdx.x, tg = blockIdx.y;
  int tid = threadIdx.x;
  int wid = tid >> 6, lane = tid & 63;
  int t = tg * 4 + wid;
  int kv = h >> 1;
  __shared__ float Ks[64][128];           // XOR-swizzled: Ks[j][d ^ (j&31)]
  __shared__ unsigned short Vs[64][128];  // bf16
  __shared__ float qs[4][128];
  for (int e = tid; e < 4 * 128; e += 256) {
    int w_ = e >> 7, dd = e & 127;
    qs[w_][dd] = qr[((tg * 4 + w_) * H_ + h) * D_ + dd];
  }
  float m = -1e30f, l = 0.f, O0 = 0.f, O1 = 0.f, pacc = 0.f;
  int nc_blk = (tg * 4 + 3) / BS_ + 1;
  int nc_me = t / BS_ + 1;
  int sw = lane & 31;
  for (int c = 0; c < nc_blk; ++c) {
    __syncthreads();
    for (int e = tid; e < 64 * 128; e += 256) {
      int j = e >> 7, dd = e & 127;
      int s = c * BS_ + j;
      Ks[j][dd ^ (j & 31)] = kr[(s * KV_ + kv) * D_ + dd];
      Vs[j][dd] = f2bf(vv[(s * KV_ + kv) * D_ + dd]);
    }
    __syncthreads();
    if (c < nc_me) {  // wave-uniform
      int s = c * BS_ + lane;
      float dot = 0.f;
#pragma unroll 8
      for (int dd = 0; dd < 128; ++dd) dot += qs[wid][dd] * Ks[lane][dd ^ sw];
      float logit = (s <= t) ? dot * SCALE_ : -1e30f;
      float mnew = fmaxf(m, wave_max(logit));
      float alpha = __expf(m - mnew);
      float p = __expf(logit - mnew);
      float ps = wave_sum(p);
      l = l * alpha + ps;
      O0 *= alpha; O1 *= alpha;
#pragma unroll 4
      for (int j = 0; j < 64; ++j) {
        float pj = __shfl(p, j, 64);
        O0 += pj * bf2f(Vs[j][lane]);
        O1 += pj * bf2f(Vs[j][lane + 64]);
      }
      pacc *= alpha;
      if (lane == c) pacc += ps;
      m = mnew;
    }
  }
  float inv = 1.f / l;
  attnb[(t * H_ + h) * D_ + lane] = O0 * inv;
  attnb[(t * H_ + h) * D_ + lane + 64] = O1 * inv;
  if (lane < NB_) pooled[(h * T_ + t) * NB_ + lane] = pacc * inv;
}

// ---------- gate loss: one wave per (kv, t>=START); writes per-(kv,t) KL sum ----------
__global__ __launch_bounds__(64) void gate_loss_kernel(const float* __restrict__ gq,
                                                       const float* __restrict__ gk,
                                                       const float* __restrict__ pooled,
                                                       float* __restrict__ klsum) {
  int kv = blockIdx.x;
  int t = START_ + blockIdx.y;
  int n = threadIdx.x;
  float dot = 0.f;
  if (n < NB_) {
    const float* a = gq + (t * KV_ + kv) * GH_;
    const float* b = gk + (n * KV_ + kv) * GH_;
    for (int d = 0; d < GH_; ++d) dot += a[d] * b[d];
  }
  bool valid = (n < NB_) && ((t / BS_) >= n);
  float score = valid ? dot * SCALE_ : -1e9f;
  float M = wave_max(score);
  float Z = wave_sum(__expf(score - M));
  float logZ = M + logf(Z);
  float g = 0.f;
  if (valid) {
    float p0 = pooled[((kv * G_) * T_ + t) * NB_ + n];
    float p1 = pooled[((kv * G_ + 1) * T_ + t) * NB_ + n];
    g = fmaxf(p0, p1);
  }
  float gs = wave_sum(g);
  float tgt = g / (gs + 1e-9f);
  float kl = (tgt > 0.f) ? tgt * (logf(tgt) - (score - logZ)) : 0.f;
  float ks = wave_sum(kl);
  if (n == 0) klsum[kv * (T_ - START_) + blockIdx.y] = ks;
}

__global__ __launch_bounds__(256) void finalize_loss(const float* __restrict__ klsum,
                                                     float* __restrict__ out) {
  const int n = KV_ * (T_ - START_);
  float s = 0.f;
  for (int i = threadIdx.x; i < n; i += 256) s += klsum[i];
  s = wave_sum(s);
  __shared__ float sh[4];
  if ((threadIdx.x & 63) == 0) sh[threadIdx.x >> 6] = s;
  __syncthreads();
  if (threadIdx.x == 0)
    out[0] = (sh[0] + sh[1] + sh[2] + sh[3]) * (1.f / ((float)(T_ - START_) * NB_));
}

extern "C" void kernel_launch(void* const* d_in, const int* in_sizes, int n_in,
                              void* d_out, int out_size, void* d_ws, size_t ws_size,
                              hipStream_t stream) {
  const float* hs   = (const float*)d_in[0];
  const float* Wq   = (const float*)d_in[1];
  const float* Wk   = (const float*)d_in[2];
  const float* Wv   = (const float*)d_in[3];
  const float* Wo   = (const float*)d_in[4];
  const float* qw   = (const float*)d_in[5];
  const float* kw   = (const float*)d_in[6];
  const float* gwq  = (const float*)d_in[7];
  const float* gwk  = (const float*)d_in[8];
  const float* cosT = (const float*)d_in[9];
  const float* sinT = (const float*)d_in[10];
  const float* cosG = (const float*)d_in[11];
  const float* sinG = (const float*)d_in[12];
  const float* cosB = (const float*)d_in[13];
  const float* sinB = (const float*)d_in[14];
  // d_in[15] = block_attention_mask: deterministic (t/BS >= n), recomputed in-kernel.
  float* out = (float*)d_out;
  float* ws = (float*)d_ws;
  float* q      = ws;                                   // T*H*D
  float* k      = q + (size_t)T_ * H_ * D_;             // T*KV*D
  float* v      = k + (size_t)T_ * KV_ * D_;            // T*KV*D
  float* knorm  = v + (size_t)T_ * KV_ * D_;            // T*KV*D
  float* qpool  = knorm + (size_t)T_ * KV_ * D_;        // T*KV*D
  float* kblk   = qpool + (size_t)T_ * KV_ * D_;        // NB*KV*D
  float* gq     = kblk + (size_t)NB_ * KV_ * D_;        // T*KV*GH
  float* gk     = gq + (size_t)T_ * KV_ * GH_;          // NB*KV*GH
  float* pooled = gk + (size_t)NB_ * KV_ * GH_;         // H*T*NB
  float* klsum  = pooled + (size_t)H_ * T_ * NB_;       // KV*(T-START)
  float* attnb  = klsum + 16384;                        // T*H*D
  // total ~76.3 MB of ws

  gemm_kernel<<<dim3(H_ * D_ / 64, T_ / 64), 256, 0, stream>>>(hs, Wq, q, T_, H_ * D_, HID_);
  gemm_kernel<<<dim3(KV_ * D_ / 64, T_ / 64), 256, 0, stream>>>(hs, Wk, k, T_, KV_ * D_, HID_);
  gemm_kernel<<<dim3(KV_ * D_ / 64, T_ / 64), 256, 0, stream>>>(hs, Wv, v, T_, KV_ * D_, HID_);
  qnorm_rope_pool<<<dim3(T_, KV_), 128, 0, stream>>>(q, qw, cosT, sinT, qpool);
  knorm_rope<<<dim3(T_, KV_), 128, 0, stream>>>(k, kw, cosT, sinT, knorm);
  kblk_kernel<<<dim3(NB_, KV_), 128, 0, stream>>>(knorm, kblk);
  gemm_kernel<<<dim3(GH_ / 64, T_ * KV_ / 64), 256, 0, stream>>>(qpool, gwq, gq, T_ * KV_, GH_, D_);
  gemm_kernel<<<dim3(GH_ / 64, NB_ * KV_ / 64), 256, 0, stream>>>(kblk, gwk, gk, NB_ * KV_, GH_, D_);
  rope_g_kernel<<<dim3(T_, KV_), 128, 0, stream>>>(gq, cosG, sinG);
  rope_g_kernel<<<dim3(NB_, KV_), 128, 0, stream>>>(gk, cosB, sinB);
  attn_kernel<<<dim3(H_, T_ / 4), 256, 0, stream>>>(q, k, v, attnb, pooled);
  gemm_kernel<<<dim3(HID_ / 64, T_ / 64), 256, 0, stream>>>(attnb, Wo, out, T_, HID_, H_ * D_);
  gate_loss_kernel<<<dim3(KV_, T_ - START_), 64, 0, stream>>>(gq, gk, pooled, klsum);
  finalize_loss<<<1, 256, 0, stream>>>(klsum, out + (size_t)T_ * HID_);
}

// Round 2
// 475.223 us; speedup vs baseline: 5.3168x; 5.3168x over previous
//
#include <hip/hip_runtime.h>

#define T_ 2048
#define HID_ 2048
#define H_ 16
#define KV_ 8
#define G_ 2
#define D_ 128
#define GH_ 128
#define BS_ 64
#define NB_ 32
#define START_ 409
#define SCALE_ 0.08838834764831845f  // 1/sqrt(128), also 1/sqrt(GH)

typedef __attribute__((ext_vector_type(8))) short short8_t;    // 8 bf16 (4 VGPRs) MFMA frag
typedef __attribute__((ext_vector_type(4))) float float4_t;    // MFMA acc
typedef __attribute__((ext_vector_type(8))) unsigned short ushort8_t;
typedef __attribute__((ext_vector_type(4))) unsigned short ushort4_t;

// ---------- helpers ----------
__device__ __forceinline__ float wave_sum(float v) {
#pragma unroll
  for (int o = 32; o > 0; o >>= 1) v += __shfl_xor(v, o, 64);
  return v;
}
__device__ __forceinline__ float wave_max(float v) {
#pragma unroll
  for (int o = 32; o > 0; o >>= 1) v = fmaxf(v, __shfl_xor(v, o, 64));
  return v;
}
__device__ __forceinline__ unsigned short f2bf(float x) {
  unsigned int u = __float_as_uint(x);
  unsigned int r = (u + 0x7fffu + ((u >> 16) & 1u)) >> 16;
  return (unsigned short)r;
}

// ---------- cast fp32 -> bf16 (flat) ----------
__global__ __launch_bounds__(256) void cast_bf16(const float* __restrict__ in,
                                                 unsigned short* __restrict__ out, int n4) {
  int i = blockIdx.x * 256 + threadIdx.x;
  if (i < n4) {
    float4 v = ((const float4*)in)[i];
    ushort4_t o = {f2bf(v.x), f2bf(v.y), f2bf(v.z), f2bf(v.w)};
    *(ushort4_t*)(out + (size_t)i * 4) = o;
  }
}

// ---------- cast+transpose: out[n][k] = bf16(in[k][n]); in row stride ldin ----------
__global__ __launch_bounds__(256) void castT(const float* __restrict__ in,
                                             unsigned short* __restrict__ out,
                                             int K, int N, int ldin) {
  __shared__ unsigned short tile[64][72];
  int k0 = blockIdx.y * 64, n0 = blockIdx.x * 64;
  int tx = threadIdx.x & 63, ty4 = threadIdx.x >> 6;
#pragma unroll
  for (int i = 0; i < 16; ++i) {
    int ky = ty4 * 16 + i;
    tile[tx][ky] = f2bf(in[(size_t)(k0 + ky) * ldin + n0 + tx]);
  }
  __syncthreads();
#pragma unroll
  for (int i = 0; i < 16; ++i) {
    int ny = ty4 * 16 + i;
    out[(size_t)(n0 + ny) * K + k0 + tx] = tile[ny][tx];
  }
}

// ---------- bf16 MFMA GEMM: C fp32[M][N] = A bf16[M][K] @ Bt bf16[N][K] ----------
// block 256 = 4 waves (2x2 of 64x64), tile 128x128, BK=32
__global__ __launch_bounds__(256) void gemm_bf16(const unsigned short* __restrict__ A,
                                                 const unsigned short* __restrict__ Bt,
                                                 float* __restrict__ C, int M, int N, int K) {
  __shared__ unsigned short As[128 * 40];  // [m][k] pad 40
  __shared__ unsigned short Bs[128 * 40];  // [n][k] pad 40
  int tid = threadIdx.x;
  int wid = tid >> 6, lane = tid & 63;
  int quad = lane >> 4, l16 = lane & 15;
  int wm = wid & 1, wn = wid >> 1;
  int m0 = blockIdx.y * 128, n0 = blockIdx.x * 128;
  float4_t acc[4][4];
#pragma unroll
  for (int i = 0; i < 4; ++i)
#pragma unroll
    for (int j = 0; j < 4; ++j) acc[i][j] = (float4_t){0.f, 0.f, 0.f, 0.f};
  for (int k0 = 0; k0 < K; k0 += 32) {
    __syncthreads();
#pragma unroll
    for (int it = 0; it < 2; ++it) {
      int ch = tid + it * 256;
      int row = ch >> 2, cp = ch & 3;
      *(ushort8_t*)&As[row * 40 + cp * 8] =
          *(const ushort8_t*)&A[(size_t)(m0 + row) * K + k0 + cp * 8];
      *(ushort8_t*)&Bs[row * 40 + cp * 8] =
          *(const ushort8_t*)&Bt[(size_t)(n0 + row) * K + k0 + cp * 8];
    }
    __syncthreads();
    short8_t a[4], b[4];
#pragma unroll
    for (int i = 0; i < 4; ++i)
      a[i] = *(const short8_t*)&As[(wm * 64 + i * 16 + l16) * 40 + quad * 8];
#pragma unroll
    for (int j = 0; j < 4; ++j)
      b[j] = *(const short8_t*)&Bs[(wn * 64 + j * 16 + l16) * 40 + quad * 8];
#pragma unroll
    for (int i = 0; i < 4; ++i)
#pragma unroll
      for (int j = 0; j < 4; ++j)
        acc[i][j] = __builtin_amdgcn_mfma_f32_16x16x32_bf16(a[i], b[j], acc[i][j], 0, 0, 0);
  }
#pragma unroll
  for (int i = 0; i < 4; ++i)
#pragma unroll
    for (int j = 0; j < 4; ++j)
#pragma unroll
      for (int reg = 0; reg < 4; ++reg)
        C[(size_t)(m0 + wm * 64 + i * 16 + quad * 4 + reg) * N + n0 + wn * 64 + j * 16 + l16] =
            acc[i][j][reg];
}

// ---------- q: rmsnorm + pool + rope; write bf16 roped q ----------
__global__ __launch_bounds__(128) void qnorm_rope_pool(const float* __restrict__ qf,
                                                       const float* __restrict__ w,
                                                       const float* __restrict__ cosT,
                                                       const float* __restrict__ sinT,
                                                       unsigned short* __restrict__ qbf,
                                                       float* __restrict__ qpool) {
  int t = blockIdx.x, kv = blockIdx.y, d = threadIdx.x;
  int i0 = t * HID_ + (kv * G_) * D_ + d;
  int i1 = i0 + D_;
  float x0 = qf[i0], x1 = qf[i1];
  __shared__ float sred[2][2];
  float s0 = wave_sum(x0 * x0), s1 = wave_sum(x1 * x1);
  if ((d & 63) == 0) { sred[0][d >> 6] = s0; sred[1][d >> 6] = s1; }
  __syncthreads();
  float wv = w[d];
  float n0 = x0 * rsqrtf((sred[0][0] + sred[0][1]) * (1.f / D_) + 1e-6f) * wv;
  float n1 = x1 * rsqrtf((sred[1][0] + sred[1][1]) * (1.f / D_) + 1e-6f) * wv;
  qpool[(t * KV_ + kv) * D_ + d] = 0.5f * (n0 + n1);
  __shared__ float sh[2][D_];
  sh[0][d] = n0; sh[1][d] = n1;
  __syncthreads();
  float c = cosT[t * D_ + d], s = sinT[t * D_ + d];
  float r0 = (d < 64) ? -sh[0][d + 64] : sh[0][d - 64];
  float r1 = (d < 64) ? -sh[1][d + 64] : sh[1][d - 64];
  qbf[((t * H_) + kv * G_) * D_ + d] = f2bf(n0 * c + r0 * s);
  qbf[((t * H_) + kv * G_ + 1) * D_ + d] = f2bf(n1 * c + r1 * s);
}

// ---------- k: rmsnorm (fp32 pre-rope to knorm) + rope -> bf16 ----------
__global__ __launch_bounds__(128) void knorm_rope(const float* __restrict__ kvf,
                                                  const float* __restrict__ w,
                                                  const float* __restrict__ cosT,
                                                  const float* __restrict__ sinT,
                                                  unsigned short* __restrict__ kbf,
                                                  float* __restrict__ knorm) {
  int t = blockIdx.x, kv = blockIdx.y, d = threadIdx.x;
  float x = kvf[t * HID_ + kv * D_ + d];
  __shared__ float sred[2];
  float s0 = wave_sum(x * x);
  if ((d & 63) == 0) sred[d >> 6] = s0;
  __syncthreads();
  float nk = x * rsqrtf((sred[0] + sred[1]) * (1.f / D_) + 1e-6f) * w[d];
  knorm[(t * KV_ + kv) * D_ + d] = nk;
  __shared__ float sh[D_];
  sh[d] = nk;
  __syncthreads();
  float rot = (d < 64) ? -sh[d + 64] : sh[d - 64];
  kbf[(t * KV_ + kv) * D_ + d] = f2bf(nk * cosT[t * D_ + d] + rot * sinT[t * D_ + d]);
}

// ---------- k_blk = mean over BS rows of knorm ----------
__global__ __launch_bounds__(128) void kblk_kernel(const float* __restrict__ knorm,
                                                   float* __restrict__ kblk) {
  int n = blockIdx.x, kv = blockIdx.y, d = threadIdx.x;
  float s = 0.f;
  for (int i = 0; i < BS_; ++i) s += knorm[((n * BS_ + i) * KV_ + kv) * D_ + d];
  kblk[(n * KV_ + kv) * D_ + d] = s * (1.f / BS_);
}

// ---------- fp32 vector GEMM for the small gate projections ----------
__global__ __launch_bounds__(256) void gemm_kernel(const float* __restrict__ A,
                                                   const float* __restrict__ B,
                                                   float* __restrict__ C,
                                                   int M, int N, int K) {
  __shared__ float Ast[16][68];
  __shared__ float Bs[16][64];
  int tid = threadIdx.x;
  int tx = tid & 15, ty = tid >> 4;
  int m0 = blockIdx.y * 64, n0 = blockIdx.x * 64;
  float acc[4][4] = {};
  for (int k0 = 0; k0 < K; k0 += 16) {
#pragma unroll
    for (int r = 0; r < 4; ++r) {
      int e = tid + 256 * r;
      int m = e >> 4, kk = e & 15;
      Ast[kk][m] = A[(size_t)(m0 + m) * K + k0 + kk];
    }
#pragma unroll
    for (int r = 0; r < 4; ++r) {
      int e = tid + 256 * r;
      int kk = e >> 6, n = e & 63;
      Bs[kk][n] = B[(size_t)(k0 + kk) * N + n0 + n];
    }
    __syncthreads();
#pragma unroll
    for (int kk = 0; kk < 16; ++kk) {
      float4 a4 = *(const float4*)&Ast[kk][ty * 4];
      float4 b4 = *(const float4*)&Bs[kk][tx * 4];
      float av[4] = {a4.x, a4.y, a4.z, a4.w};
      float bv[4] = {b4.x, b4.y, b4.z, b4.w};
#pragma unroll
      for (int i = 0; i < 4; ++i)
#pragma unroll
        for (int j = 0; j < 4; ++j) acc[i][j] += av[i] * bv[j];
    }
    __syncthreads();
  }
#pragma unroll
  for (int i = 0; i < 4; ++i)
#pragma unroll
    for (int j = 0; j < 4; ++j)
      C[(size_t)(m0 + ty * 4 + i) * N + n0 + tx * 4 + j] = acc[i][j];
}

// ---------- generic rope over (rows, KV, GH) ----------
__global__ __launch_bounds__(128) void rope_g_kernel(float* x, const float* __restrict__ cs,
                                                     const float* __restrict__ sn) {
  int r = blockIdx.x, kv = blockIdx.y, d = threadIdx.x;
  int base = (r * KV_ + kv) * GH_;
  __shared__ float sh[GH_];
  sh[d] = x[base + d];
  __syncthreads();
  float rot = (d < 64) ? -sh[d + 64] : sh[d - 64];
  x[base + d] = sh[d] * cs[r * GH_ + d] + rot * sn[r * GH_ + d];
}

// ---------- MFMA flash attention ----------
// grid (H, T/64); block 256 = 4 waves x 16 q-rows; chunk = 64 keys
__global__ __launch_bounds__(256) void attn_mfma(const unsigned short* __restrict__ qbf,
                                                 const unsigned short* __restrict__ kbf,
                                                 const unsigned short* __restrict__ vt,
                                                 unsigned short* __restrict__ attnb,
                                                 float* __restrict__ pooled) {
  int h = blockIdx.x, tile = blockIdx.y;
  int t0 = tile * 64;
  int tid = threadIdx.x;
  int wid = tid >> 6, lane = tid & 63;
  int quad = lane >> 4, l16 = lane & 15;
  int kv = h >> 1;
  __shared__ unsigned short Ks[64 * 136];      // K chunk [s][d], pad 8
  __shared__ unsigned short Vs[128 * 72];      // V chunk transposed [d][s], pad 8
  __shared__ unsigned short Ps[4][16 * 72];    // per-wave P [r][s], pad 8

  // Q fragments: 16 rows x 128 d per wave, cached in regs
  int tq = t0 + wid * 16 + l16;
  short8_t qf[4];
#pragma unroll
  for (int kb = 0; kb < 4; ++kb)
    qf[kb] = *(const short8_t*)&qbf[((size_t)tq * H_ + h) * D_ + kb * 32 + quad * 8];

  int tbase = t0 + wid * 16 + quad * 4;
  float m_[4], l_[4], pacc[2][4];
  float4_t o[8];
#pragma unroll
  for (int r = 0; r < 4; ++r) { m_[r] = -1e30f; l_[r] = 0.f; pacc[0][r] = 0.f; pacc[1][r] = 0.f; }
#pragma unroll
  for (int j = 0; j < 8; ++j) o[j] = (float4_t){0.f, 0.f, 0.f, 0.f};

  int nchunks = tile + 1;
  for (int c = 0; c < nchunks; ++c) {
    __syncthreads();
    // stage K: 64 rows x 256B
#pragma unroll
    for (int it = 0; it < 4; ++it) {
      int ch = tid + it * 256;
      int row = ch >> 4, cp = ch & 15;
      *(ushort8_t*)&Ks[row * 136 + cp * 8] =
          *(const ushort8_t*)&kbf[(((size_t)(c * 64 + row)) * KV_ + kv) * D_ + cp * 8];
    }
    // stage Vt: 128 rows x 128B
#pragma unroll
    for (int it = 0; it < 4; ++it) {
      int ch = tid + it * 256;
      int row = ch >> 3, cp = ch & 7;
      *(ushort8_t*)&Vs[row * 72 + cp * 8] =
          *(const ushort8_t*)&vt[((size_t)(kv * 128 + row)) * T_ + c * 64 + cp * 8];
    }
    __syncthreads();

    // ---- QK^T: S 16x64 per wave ----
    float4_t s[4];
#pragma unroll
    for (int j = 0; j < 4; ++j) {
      float4_t a = (float4_t){0.f, 0.f, 0.f, 0.f};
#pragma unroll
      for (int kb = 0; kb < 4; ++kb) {
        short8_t kf = *(const short8_t*)&Ks[(j * 16 + l16) * 136 + kb * 32 + quad * 8];
        a = __builtin_amdgcn_mfma_f32_16x16x32_bf16(qf[kb], kf, a, 0, 0, 0);
      }
      s[j] = a;
    }
    // mask + scale + row max (quad-local reduce)
    float rowmax[4];
    if (c == tile) {
#pragma unroll
      for (int reg = 0; reg < 4; ++reg) {
        int trow = tbase + reg;
        float mx = -1e30f;
#pragma unroll
        for (int j = 0; j < 4; ++j) {
          float lv = (c * 64 + j * 16 + l16 <= trow) ? s[j][reg] * SCALE_ : -1e30f;
          s[j][reg] = lv;
          mx = fmaxf(mx, lv);
        }
        rowmax[reg] = mx;
      }
    } else {
#pragma unroll
      for (int reg = 0; reg < 4; ++reg) {
        float mx = -1e30f;
#pragma unroll
        for (int j = 0; j < 4; ++j) {
          float lv = s[j][reg] * SCALE_;
          s[j][reg] = lv;
          mx = fmaxf(mx, lv);
        }
        rowmax[reg] = mx;
      }
    }
#pragma unroll
    for (int reg = 0; reg < 4; ++reg) {
#pragma unroll
      for (int off = 1; off < 16; off <<= 1)
        rowmax[reg] = fmaxf(rowmax[reg], __shfl_xor(rowmax[reg], off, 64));
    }
    float alpha[4], ps[4];
#pragma unroll
    for (int reg = 0; reg < 4; ++reg) {
      float mnew = fmaxf(m_[reg], rowmax[reg]);
      alpha[reg] = __expf(m_[reg] - mnew);
      m_[reg] = mnew;
      ps[reg] = 0.f;
    }
#pragma unroll
    for (int j = 0; j < 4; ++j)
#pragma unroll
      for (int reg = 0; reg < 4; ++reg) {
        float p = __expf(s[j][reg] - m_[reg]);
        s[j][reg] = p;
        ps[reg] += p;
      }
#pragma unroll
    for (int reg = 0; reg < 4; ++reg) {
#pragma unroll
      for (int off = 1; off < 16; off <<= 1) ps[reg] += __shfl_xor(ps[reg], off, 64);
      l_[reg] = l_[reg] * alpha[reg] + ps[reg];
    }
    // pooled accumulator: lane l16 owns chunks with (c&15)==l16, half = c>>4
    int half = c >> 4, cl = c & 15;
#pragma unroll
    for (int reg = 0; reg < 4; ++reg) {
      pacc[0][reg] *= alpha[reg];
      pacc[1][reg] *= alpha[reg];
      if (l16 == cl) pacc[half][reg] += ps[reg];
    }
    // write P (C layout) -> LDS bf16 [r][s]
#pragma unroll
    for (int j = 0; j < 4; ++j)
#pragma unroll
      for (int reg = 0; reg < 4; ++reg)
        Ps[wid][(quad * 4 + reg) * 72 + j * 16 + l16] = f2bf(s[j][reg]);
    // rescale O
#pragma unroll
    for (int jt = 0; jt < 8; ++jt)
#pragma unroll
      for (int reg = 0; reg < 4; ++reg) o[jt][reg] *= alpha[reg];
    // ---- PV: O 16x128 per wave ----
#pragma unroll
    for (int ks = 0; ks < 2; ++ks) {
      short8_t pf = *(const short8_t*)&Ps[wid][l16 * 72 + ks * 32 + quad * 8];
#pragma unroll
      for (int jt = 0; jt < 8; ++jt) {
        short8_t vf = *(const short8_t*)&Vs[(jt * 16 + l16) * 72 + ks * 32 + quad * 8];
        o[jt] = __builtin_amdgcn_mfma_f32_16x16x32_bf16(pf, vf, o[jt], 0, 0, 0);
      }
    }
  }
  // epilogue
  float inv[4];
#pragma unroll
  for (int reg = 0; reg < 4; ++reg) inv[reg] = 1.f / l_[reg];
#pragma unroll
  for (int jt = 0; jt < 8; ++jt)
#pragma unroll
    for (int reg = 0; reg < 4; ++reg)
      attnb[(size_t)(tbase + reg) * (H_ * D_) + h * D_ + jt * 16 + l16] =
          f2bf(o[jt][reg] * inv[reg]);
#pragma unroll
  for (int reg = 0; reg < 4; ++reg) {
    int trow = tbase + reg;
    pooled[((size_t)h * T_ + trow) * NB_ + l16] = pacc[0][reg] * inv[reg];
    pooled[((size_t)h * T_ + trow) * NB_ + 16 + l16] = pacc[1][reg] * inv[reg];
  }
}

// ---------- gate loss ----------
__global__ __launch_bounds__(64) void gate_loss_kernel(const float* __restrict__ gq,
                                                       const float* __restrict__ gk,
                                                       const float* __restrict__ pooled,
                                                       float* __restrict__ klsum) {
  int kv = blockIdx.x;
  int t = START_ + blockIdx.y;
  int n = threadIdx.x;
  float dot = 0.f;
  if (n < NB_) {
    const float* a = gq + (t * KV_ + kv) * GH_;
    const float* b = gk + (n * KV_ + kv) * GH_;
    for (int d = 0; d < GH_; ++d) dot += a[d] * b[d];
  }
  bool valid = (n < NB_) && ((t / BS_) >= n);
  float score = valid ? dot * SCALE_ : -1e9f;
  float M = wave_max(score);
  float Z = wave_sum(__expf(score - M));
  float logZ = M + logf(Z);
  float g = 0.f;
  if (valid) {
    float p0 = pooled[((kv * G_) * T_ + t) * NB_ + n];
    float p1 = pooled[((kv * G_ + 1) * T_ + t) * NB_ + n];
    g = fmaxf(p0, p1);
  }
  float gs = wave_sum(g);
  float tgt = g / (gs + 1e-9f);
  float kl = (tgt > 0.f) ? tgt * (logf(tgt) - (score - logZ)) : 0.f;
  float ks = wave_sum(kl);
  if (n == 0) klsum[kv * (T_ - START_) + blockIdx.y] = ks;
}

__global__ __launch_bounds__(256) void finalize_loss(const float* __restrict__ klsum,
                                                     float* __restrict__ out) {
  const int n = KV_ * (T_ - START_);
  float s = 0.f;
  for (int i = threadIdx.x; i < n; i += 256) s += klsum[i];
  s = wave_sum(s);
  __shared__ float sh[4];
  if ((threadIdx.x & 63) == 0) sh[threadIdx.x >> 6] = s;
  __syncthreads();
  if (threadIdx.x == 0)
    out[0] = (sh[0] + sh[1] + sh[2] + sh[3]) * (1.f / ((float)(T_ - START_) * NB_));
}

extern "C" void kernel_launch(void* const* d_in, const int* in_sizes, int n_in,
                              void* d_out, int out_size, void* d_ws, size_t ws_size,
                              hipStream_t stream) {
  const float* hs   = (const float*)d_in[0];
  const float* Wq   = (const float*)d_in[1];
  const float* Wk   = (const float*)d_in[2];
  const float* Wv   = (const float*)d_in[3];
  const float* Wo   = (const float*)d_in[4];
  const float* qw   = (const float*)d_in[5];
  const float* kw   = (const float*)d_in[6];
  const float* gwq  = (const float*)d_in[7];
  const float* gwk  = (const float*)d_in[8];
  const float* cosT = (const float*)d_in[9];
  const float* sinT = (const float*)d_in[10];
  const float* cosG = (const float*)d_in[11];
  const float* sinG = (const float*)d_in[12];
  const float* cosB = (const float*)d_in[13];
  const float* sinB = (const float*)d_in[14];
  float* out = (float*)d_out;
  float* ws = (float*)d_ws;

  // ---- workspace layout (float offsets), with lifetime-based aliasing ----
  const size_t MEG = 1048576;
  float*          kvf    = ws;                                  // 4M floats [T][2048] (k|v proj)
  float*          pooled = ws;                                  // alias: kvf dead after vcastT
  float*          qf     = ws + 4 * MEG;                        // 4M floats [T][2048] q proj
  unsigned short* attnb  = (unsigned short*)(ws + 4 * MEG);     // alias qf: 4M ushorts
  float*          knorm  = ws + 6 * MEG;                        // 2M floats (qf 2nd half, after qnorm)
  float*          qpool  = ws + 8 * MEG;                        // 2M floats
  unsigned short* WoT    = (unsigned short*)(ws + 10 * MEG);    // 4M ushorts
  unsigned short* WqT    = (unsigned short*)(ws + 12 * MEG);    // 4M ushorts
  unsigned short* qbf    = WqT;                                 // alias after q GEMM
  unsigned short* WkvT   = (unsigned short*)(ws + 14 * MEG);    // 4M ushorts
  unsigned short* kbf    = WkvT;                                // alias: 2M ushorts
  unsigned short* vt     = WkvT + 2 * MEG;                      // alias: 2M ushorts [kv*D][T]
  unsigned short* hsb    = (unsigned short*)(ws + 16 * MEG);    // 4M ushorts
  float*          gq     = ws + 16 * MEG;                       // alias hsb: 2M floats
  float*          kblk   = ws + 18 * MEG;                       // 32K floats
  float*          gk     = ws + 18 * MEG + 32768;               // 32K floats
  float*          klsum  = ws + 18 * MEG + 65536;               // ~13K floats
  // total ~75.9 MB

  // casts
  cast_bf16<<<4096, 256, 0, stream>>>(hs, hsb, 1048576);
  castT<<<dim3(32, 32), 256, 0, stream>>>(Wq, WqT, HID_, 2048, 2048);
  castT<<<dim3(16, 32), 256, 0, stream>>>(Wk, WkvT, HID_, 1024, 1024);
  castT<<<dim3(16, 32), 256, 0, stream>>>(Wv, WkvT + 1024 * (size_t)HID_, HID_, 1024, 1024);
  castT<<<dim3(32, 32), 256, 0, stream>>>(Wo, WoT, 2048, 2048, 2048);
  // projections (bf16 MFMA)
  gemm_bf16<<<dim3(16, 16), 256, 0, stream>>>(hsb, WqT, qf, T_, 2048, HID_);
  gemm_bf16<<<dim3(16, 16), 256, 0, stream>>>(hsb, WkvT, kvf, T_, 2048, HID_);
  // norms + rope (qbf overwrites WqT; kbf overwrites WkvT — both dead)
  qnorm_rope_pool<<<dim3(T_, KV_), 128, 0, stream>>>(qf, qw, cosT, sinT, qbf, qpool);
  knorm_rope<<<dim3(T_, KV_), 128, 0, stream>>>(kvf, kw, cosT, sinT, kbf, knorm);
  // v transpose-cast: vt[cc][t] = bf16(kvf[t][1024+cc])
  castT<<<dim3(16, 32), 256, 0, stream>>>(kvf + 1024, vt, T_, 1024, 2048);
  kblk_kernel<<<dim3(NB_, KV_), 128, 0, stream>>>(knorm, kblk);
  // gate projections (small, fp32)
  gemm_kernel<<<dim3(GH_ / 64, T_ * KV_ / 64), 256, 0, stream>>>(qpool, gwq, gq, T_ * KV_, GH_, D_);
  gemm_kernel<<<dim3(GH_ / 64, NB_ * KV_ / 64), 256, 0, stream>>>(kblk, gwk, gk, NB_ * KV_, GH_, D_);
  rope_g_kernel<<<dim3(T_, KV_), 128, 0, stream>>>(gq, cosG, sinG);
  rope_g_kernel<<<dim3(NB_, KV_), 128, 0, stream>>>(gk, cosB, sinB);
  // attention (MFMA flash) — writes attnb (qf region) + pooled (kvf region)
  attn_mfma<<<dim3(H_, T_ / 64), 256, 0, stream>>>(qbf, kbf, vt, attnb, pooled);
  // output projection
  gemm_bf16<<<dim3(16, 16), 256, 0, stream>>>(attnb, WoT, out, T_, HID_, H_ * D_);
  // gate loss
  gate_loss_kernel<<<dim3(KV_, T_ - START_), 64, 0, stream>>>(gq, gk, pooled, klsum);
  finalize_loss<<<1, 256, 0, stream>>>(klsum, out + (size_t)T_ * HID_);
}

// Round 3
// 413.327 us; speedup vs baseline: 6.1130x; 1.1497x over previous
//
#include <hip/hip_runtime.h>

#define T_ 2048
#define HID_ 2048
#define H_ 16
#define KV_ 8
#define G_ 2
#define D_ 128
#define GH_ 128
#define BS_ 64
#define NB_ 32
#define START_ 409
#define TG0_ 384  // first multiple-of-128*... row block covering START (gq computed for t>=384)
#define SCALE_ 0.08838834764831845f  // 1/sqrt(128), also 1/sqrt(GH)

typedef __attribute__((ext_vector_type(8))) short short8_t;
typedef __attribute__((ext_vector_type(4))) float float4_t;
typedef __attribute__((ext_vector_type(8))) unsigned short ushort8_t;
typedef __attribute__((ext_vector_type(4))) unsigned short ushort4_t;

// ---------- helpers ----------
__device__ __forceinline__ float wave_sum(float v) {
#pragma unroll
  for (int o = 32; o > 0; o >>= 1) v += __shfl_xor(v, o, 64);
  return v;
}
__device__ __forceinline__ float wave_max(float v) {
#pragma unroll
  for (int o = 32; o > 0; o >>= 1) v = fmaxf(v, __shfl_xor(v, o, 64));
  return v;
}
__device__ __forceinline__ unsigned short f2bf(float x) {
  unsigned int u = __float_as_uint(x);
  unsigned int r = (u + 0x7fffu + ((u >> 16) & 1u)) >> 16;
  return (unsigned short)r;
}

// async global->LDS 16B per lane; lds base must be wave-uniform (lane lands at base+lane*16)
__device__ __forceinline__ void gload16(const void* g, void* l) {
  __builtin_amdgcn_global_load_lds((const __attribute__((address_space(1))) unsigned int*)g,
                                   (__attribute__((address_space(3))) unsigned int*)l, 16, 0, 0);
}

// ---------- cast fp32 -> bf16 (flat, n4 = count/4) ----------
__global__ __launch_bounds__(256) void cast_bf16(const float* __restrict__ in,
                                                 unsigned short* __restrict__ out, int n4) {
  int i = blockIdx.x * 256 + threadIdx.x;
  if (i < n4) {
    float4 v = ((const float4*)in)[i];
    ushort4_t o = {f2bf(v.x), f2bf(v.y), f2bf(v.z), f2bf(v.w)};
    *(ushort4_t*)(out + (size_t)i * 4) = o;
  }
}

// ---------- cast+transpose: out[n][k] = bf16(in[k][n]); in row stride ldin, out row stride K ----------
__global__ __launch_bounds__(256) void castT(const float* __restrict__ in,
                                             unsigned short* __restrict__ out,
                                             int K, int N, int ldin) {
  __shared__ unsigned short tile[64][72];
  int k0 = blockIdx.y * 64, n0 = blockIdx.x * 64;
  int tx = threadIdx.x & 63, ty4 = threadIdx.x >> 6;
#pragma unroll
  for (int i = 0; i < 16; ++i) {
    int ky = ty4 * 16 + i;
    tile[tx][ky] = f2bf(in[(size_t)(k0 + ky) * ldin + n0 + tx]);
  }
  __syncthreads();
#pragma unroll
  for (int i = 0; i < 16; ++i) {
    int ny = ty4 * 16 + i;
    out[(size_t)(n0 + ny) * K + k0 + tx] = tile[ny][tx];
  }
}

// ---------- bf16 MFMA GEMM v2 (m97-style): C fp32[M][ldc] = A bf16[M][K] @ Bt bf16[N][K] ----------
// 256 thr = 4 waves (2x2 of 64x64), tile 128x128, BK=32, global_load_lds staging (unpadded LDS)
__global__ __launch_bounds__(256) void gemm_bf16_v2(const unsigned short* __restrict__ A,
                                                    const unsigned short* __restrict__ Bt,
                                                    float* __restrict__ C,
                                                    int M, int N, int K, int ldc) {
  __shared__ unsigned short As[128 * 32];
  __shared__ unsigned short Bs[128 * 32];
  int tid = threadIdx.x;
  int wid = tid >> 6, lane = tid & 63;
  int quad = lane >> 4, l16 = lane & 15;
  int wm = wid & 1, wn = wid >> 1;
  int m0 = blockIdx.y * 128, n0 = blockIdx.x * 128;
  // staging geometry: linear ushort e = j*2048 + wid*512 + lane*8; row=e>>5, col=e&31
  int e0 = wid * 512 + lane * 8;
  int r0 = e0 >> 5, c0 = e0 & 31;
  const unsigned short* ga0 = A + (size_t)(m0 + r0) * K + c0;
  const unsigned short* ga1 = A + (size_t)(m0 + r0 + 64) * K + c0;
  const unsigned short* gb0 = Bt + (size_t)(n0 + r0) * K + c0;
  const unsigned short* gb1 = Bt + (size_t)(n0 + r0 + 64) * K + c0;
  unsigned short* lA0 = As + wid * 512;
  unsigned short* lA1 = As + 2048 + wid * 512;
  unsigned short* lB0 = Bs + wid * 512;
  unsigned short* lB1 = Bs + 2048 + wid * 512;
  float4_t acc[4][4];
#pragma unroll
  for (int i = 0; i < 4; ++i)
#pragma unroll
    for (int j = 0; j < 4; ++j) acc[i][j] = (float4_t){0.f, 0.f, 0.f, 0.f};
  for (int k0 = 0; k0 < K; k0 += 32) {
    __syncthreads();
    gload16(ga0 + k0, lA0);
    gload16(ga1 + k0, lA1);
    gload16(gb0 + k0, lB0);
    gload16(gb1 + k0, lB1);
    __syncthreads();
    short8_t a[4], b[4];
#pragma unroll
    for (int i = 0; i < 4; ++i)
      a[i] = *(const short8_t*)&As[(wm * 64 + i * 16 + l16) * 32 + quad * 8];
#pragma unroll
    for (int j = 0; j < 4; ++j)
      b[j] = *(const short8_t*)&Bs[(wn * 64 + j * 16 + l16) * 32 + quad * 8];
#pragma unroll
    for (int i = 0; i < 4; ++i)
#pragma unroll
      for (int j = 0; j < 4; ++j)
        acc[i][j] = __builtin_amdgcn_mfma_f32_16x16x32_bf16(a[i], b[j], acc[i][j], 0, 0, 0);
  }
#pragma unroll
  for (int i = 0; i < 4; ++i)
#pragma unroll
    for (int j = 0; j < 4; ++j)
#pragma unroll
      for (int reg = 0; reg < 4; ++reg)
        C[(size_t)(m0 + wm * 64 + i * 16 + quad * 4 + reg) * ldc + n0 + wn * 64 + j * 16 + l16] =
            acc[i][j][reg];
}

// ---------- q: rmsnorm + pool (bf16, t>=TG0 only) + rope -> bf16; reads merged qkvf ----------
__global__ __launch_bounds__(128) void qnorm_rope_pool(const float* __restrict__ qkvf,
                                                       const float* __restrict__ w,
                                                       const float* __restrict__ cosT,
                                                       const float* __restrict__ sinT,
                                                       unsigned short* __restrict__ qbf,
                                                       unsigned short* __restrict__ qpool_bf) {
  int t = blockIdx.x, kv = blockIdx.y, d = threadIdx.x;
  size_t i0 = (size_t)t * 4096 + (kv * G_) * D_ + d;
  size_t i1 = i0 + D_;
  float x0 = qkvf[i0], x1 = qkvf[i1];
  __shared__ float sred[2][2];
  float s0 = wave_sum(x0 * x0), s1 = wave_sum(x1 * x1);
  if ((d & 63) == 0) { sred[0][d >> 6] = s0; sred[1][d >> 6] = s1; }
  __syncthreads();
  float wv = w[d];
  float n0 = x0 * rsqrtf((sred[0][0] + sred[0][1]) * (1.f / D_) + 1e-6f) * wv;
  float n1 = x1 * rsqrtf((sred[1][0] + sred[1][1]) * (1.f / D_) + 1e-6f) * wv;
  if (t >= TG0_) qpool_bf[((size_t)(t - TG0_) * KV_ + kv) * D_ + d] = f2bf(0.5f * (n0 + n1));
  __shared__ float sh[2][D_];
  sh[0][d] = n0; sh[1][d] = n1;
  __syncthreads();
  float c = cosT[t * D_ + d], s = sinT[t * D_ + d];
  float r0 = (d < 64) ? -sh[0][d + 64] : sh[0][d - 64];
  float r1 = (d < 64) ? -sh[1][d + 64] : sh[1][d - 64];
  qbf[((size_t)(t * H_) + kv * G_) * D_ + d] = f2bf(n0 * c + r0 * s);
  qbf[((size_t)(t * H_) + kv * G_ + 1) * D_ + d] = f2bf(n1 * c + r1 * s);
}

// ---------- k: rmsnorm (fp32 pre-rope) + rope -> bf16; reads merged qkvf ----------
__global__ __launch_bounds__(128) void knorm_rope(const float* __restrict__ qkvf,
                                                  const float* __restrict__ w,
                                                  const float* __restrict__ cosT,
                                                  const float* __restrict__ sinT,
                                                  unsigned short* __restrict__ kbf,
                                                  float* __restrict__ knorm) {
  int t = blockIdx.x, kv = blockIdx.y, d = threadIdx.x;
  float x = qkvf[(size_t)t * 4096 + 2048 + kv * D_ + d];
  __shared__ float sred[2];
  float s0 = wave_sum(x * x);
  if ((d & 63) == 0) sred[d >> 6] = s0;
  __syncthreads();
  float nk = x * rsqrtf((sred[0] + sred[1]) * (1.f / D_) + 1e-6f) * w[d];
  knorm[(size_t)(t * KV_ + kv) * D_ + d] = nk;
  __shared__ float sh[D_];
  sh[d] = nk;
  __syncthreads();
  float rot = (d < 64) ? -sh[d + 64] : sh[d - 64];
  kbf[(size_t)(t * KV_ + kv) * D_ + d] = f2bf(nk * cosT[t * D_ + d] + rot * sinT[t * D_ + d]);
}

// ---------- k_blk = mean over BS rows of knorm -> bf16 ----------
__global__ __launch_bounds__(128) void kblk_kernel(const float* __restrict__ knorm,
                                                   unsigned short* __restrict__ kblk_bf) {
  int n = blockIdx.x, kv = blockIdx.y, d = threadIdx.x;
  float s = 0.f;
  for (int i = 0; i < BS_; ++i) s += knorm[((size_t)(n * BS_ + i) * KV_ + kv) * D_ + d];
  kblk_bf[(size_t)(n * KV_ + kv) * D_ + d] = f2bf(s * (1.f / BS_));
}

// ---------- rope over (rows, KV, GH) ----------
__global__ __launch_bounds__(128) void rope_g_kernel(float* x, const float* __restrict__ cs,
                                                     const float* __restrict__ sn) {
  int r = blockIdx.x, kv = blockIdx.y, d = threadIdx.x;
  size_t base = (size_t)(r * KV_ + kv) * GH_;
  __shared__ float sh[GH_];
  sh[d] = x[base + d];
  __syncthreads();
  float rot = (d < 64) ? -sh[d + 64] : sh[d - 64];
  x[base + d] = sh[d] * cs[r * GH_ + d] + rot * sn[r * GH_ + d];
}

// ---------- MFMA flash attention ----------
// grid (H, 32); tile remap pairs (y, y+16)->(y, 31-y) so co-resident blocks sum to 33 chunks
__global__ __launch_bounds__(256) void attn_mfma(const unsigned short* __restrict__ qbf,
                                                 const unsigned short* __restrict__ kbf,
                                                 const unsigned short* __restrict__ vt,
                                                 unsigned short* __restrict__ attnb,
                                                 float* __restrict__ pooled) {
  int h = blockIdx.x;
  int yy = blockIdx.y;
  int tile = (yy < 16) ? yy : 47 - yy;  // uniform pairing: (y)+(y+16) -> 33 chunks
  int t0 = tile * 64;
  int tid = threadIdx.x;
  int wid = tid >> 6, lane = tid & 63;
  int quad = lane >> 4, l16 = lane & 15;
  int kv = h >> 1;
  __shared__ unsigned short Ks[64 * 136];      // [s][d], pad 8
  __shared__ unsigned short Vs[128 * 72];      // [d][s], pad 8
  __shared__ unsigned short Ps[4][16 * 72];    // per-wave P [r][s], pad 8

  int tq = t0 + wid * 16 + l16;
  short8_t qf[4];
#pragma unroll
  for (int kb = 0; kb < 4; ++kb)
    qf[kb] = *(const short8_t*)&qbf[((size_t)tq * H_ + h) * D_ + kb * 32 + quad * 8];

  int tbase = t0 + wid * 16 + quad * 4;
  float m_[4], l_[4], pacc[2][4];
  float4_t o[8];
#pragma unroll
  for (int r = 0; r < 4; ++r) { m_[r] = -1e30f; l_[r] = 0.f; pacc[0][r] = 0.f; pacc[1][r] = 0.f; }
#pragma unroll
  for (int j = 0; j < 8; ++j) o[j] = (float4_t){0.f, 0.f, 0.f, 0.f};

  int nchunks = tile + 1;
  for (int c = 0; c < nchunks; ++c) {
    __syncthreads();
#pragma unroll
    for (int it = 0; it < 4; ++it) {
      int ch = tid + it * 256;
      int row = ch >> 4, cp = ch & 15;
      *(ushort8_t*)&Ks[row * 136 + cp * 8] =
          *(const ushort8_t*)&kbf[(((size_t)(c * 64 + row)) * KV_ + kv) * D_ + cp * 8];
    }
#pragma unroll
    for (int it = 0; it < 4; ++it) {
      int ch = tid + it * 256;
      int row = ch >> 3, cp = ch & 7;
      *(ushort8_t*)&Vs[row * 72 + cp * 8] =
          *(const ushort8_t*)&vt[((size_t)(kv * 128 + row)) * T_ + c * 64 + cp * 8];
    }
    __syncthreads();

    float4_t s[4];
#pragma unroll
    for (int j = 0; j < 4; ++j) {
      float4_t a = (float4_t){0.f, 0.f, 0.f, 0.f};
#pragma unroll
      for (int kb = 0; kb < 4; ++kb) {
        short8_t kf = *(const short8_t*)&Ks[(j * 16 + l16) * 136 + kb * 32 + quad * 8];
        a = __builtin_amdgcn_mfma_f32_16x16x32_bf16(qf[kb], kf, a, 0, 0, 0);
      }
      s[j] = a;
    }
    float rowmax[4];
    if (c == tile) {
#pragma unroll
      for (int reg = 0; reg < 4; ++reg) {
        int trow = tbase + reg;
        float mx = -1e30f;
#pragma unroll
        for (int j = 0; j < 4; ++j) {
          float lv = (c * 64 + j * 16 + l16 <= trow) ? s[j][reg] * SCALE_ : -1e30f;
          s[j][reg] = lv;
          mx = fmaxf(mx, lv);
        }
        rowmax[reg] = mx;
      }
    } else {
#pragma unroll
      for (int reg = 0; reg < 4; ++reg) {
        float mx = -1e30f;
#pragma unroll
        for (int j = 0; j < 4; ++j) {
          float lv = s[j][reg] * SCALE_;
          s[j][reg] = lv;
          mx = fmaxf(mx, lv);
        }
        rowmax[reg] = mx;
      }
    }
#pragma unroll
    for (int reg = 0; reg < 4; ++reg) {
#pragma unroll
      for (int off = 1; off < 16; off <<= 1)
        rowmax[reg] = fmaxf(rowmax[reg], __shfl_xor(rowmax[reg], off, 64));
    }
    float alpha[4], ps[4];
#pragma unroll
    for (int reg = 0; reg < 4; ++reg) {
      float mnew = fmaxf(m_[reg], rowmax[reg]);
      alpha[reg] = __expf(m_[reg] - mnew);
      m_[reg] = mnew;
      ps[reg] = 0.f;
    }
#pragma unroll
    for (int j = 0; j < 4; ++j)
#pragma unroll
      for (int reg = 0; reg < 4; ++reg) {
        float p = __expf(s[j][reg] - m_[reg]);
        s[j][reg] = p;
        ps[reg] += p;
      }
#pragma unroll
    for (int reg = 0; reg < 4; ++reg) {
#pragma unroll
      for (int off = 1; off < 16; off <<= 1) ps[reg] += __shfl_xor(ps[reg], off, 64);
      l_[reg] = l_[reg] * alpha[reg] + ps[reg];
    }
    int half = c >> 4, cl = c & 15;
#pragma unroll
    for (int reg = 0; reg < 4; ++reg) {
      pacc[0][reg] *= alpha[reg];
      pacc[1][reg] *= alpha[reg];
      if (l16 == cl) pacc[half][reg] += ps[reg];
    }
#pragma unroll
    for (int j = 0; j < 4; ++j)
#pragma unroll
      for (int reg = 0; reg < 4; ++reg)
        Ps[wid][(quad * 4 + reg) * 72 + j * 16 + l16] = f2bf(s[j][reg]);
#pragma unroll
    for (int jt = 0; jt < 8; ++jt)
#pragma unroll
      for (int reg = 0; reg < 4; ++reg) o[jt][reg] *= alpha[reg];
#pragma unroll
    for (int ks = 0; ks < 2; ++ks) {
      short8_t pf = *(const short8_t*)&Ps[wid][l16 * 72 + ks * 32 + quad * 8];
#pragma unroll
      for (int jt = 0; jt < 8; ++jt) {
        short8_t vf = *(const short8_t*)&Vs[(jt * 16 + l16) * 72 + ks * 32 + quad * 8];
        o[jt] = __builtin_amdgcn_mfma_f32_16x16x32_bf16(pf, vf, o[jt], 0, 0, 0);
      }
    }
  }
  float inv[4];
#pragma unroll
  for (int reg = 0; reg < 4; ++reg) inv[reg] = 1.f / l_[reg];
#pragma unroll
  for (int jt = 0; jt < 8; ++jt)
#pragma unroll
    for (int reg = 0; reg < 4; ++reg)
      attnb[(size_t)(tbase + reg) * (H_ * D_) + h * D_ + jt * 16 + l16] =
          f2bf(o[jt][reg] * inv[reg]);
#pragma unroll
  for (int reg = 0; reg < 4; ++reg) {
    int trow = tbase + reg;
    pooled[((size_t)h * T_ + trow) * NB_ + l16] = pacc[0][reg] * inv[reg];
    pooled[((size_t)h * T_ + trow) * NB_ + 16 + l16] = pacc[1][reg] * inv[reg];
  }
}

// ---------- gate loss ----------
__global__ __launch_bounds__(64) void gate_loss_kernel(const float* __restrict__ gq,
                                                       const float* __restrict__ gk,
                                                       const float* __restrict__ pooled,
                                                       float* __restrict__ klsum) {
  int kv = blockIdx.x;
  int t = START_ + blockIdx.y;
  int n = threadIdx.x;
  float dot = 0.f;
  if (n < NB_) {
    const float* a = gq + ((size_t)(t - TG0_) * KV_ + kv) * GH_;
    const float* b = gk + (size_t)(n * KV_ + kv) * GH_;
    for (int d = 0; d < GH_; ++d) dot += a[d] * b[d];
  }
  bool valid = (n < NB_) && ((t / BS_) >= n);
  float score = valid ? dot * SCALE_ : -1e9f;
  float M = wave_max(score);
  float Z = wave_sum(__expf(score - M));
  float logZ = M + logf(Z);
  float g = 0.f;
  if (valid) {
    float p0 = pooled[((size_t)(kv * G_) * T_ + t) * NB_ + n];
    float p1 = pooled[((size_t)(kv * G_ + 1) * T_ + t) * NB_ + n];
    g = fmaxf(p0, p1);
  }
  float gs = wave_sum(g);
  float tgt = g / (gs + 1e-9f);
  float kl = (tgt > 0.f) ? tgt * (logf(tgt) - (score - logZ)) : 0.f;
  float ks = wave_sum(kl);
  if (n == 0) klsum[kv * (T_ - START_) + blockIdx.y] = ks;
}

__global__ __launch_bounds__(256) void finalize_loss(const float* __restrict__ klsum,
                                                     float* __restrict__ out) {
  const int n = KV_ * (T_ - START_);
  float s = 0.f;
  for (int i = threadIdx.x; i < n; i += 256) s += klsum[i];
  s = wave_sum(s);
  __shared__ float sh[4];
  if ((threadIdx.x & 63) == 0) sh[threadIdx.x >> 6] = s;
  __syncthreads();
  if (threadIdx.x == 0)
    out[0] = (sh[0] + sh[1] + sh[2] + sh[3]) * (1.f / ((float)(T_ - START_) * NB_));
}

extern "C" void kernel_launch(void* const* d_in, const int* in_sizes, int n_in,
                              void* d_out, int out_size, void* d_ws, size_t ws_size,
                              hipStream_t stream) {
  const float* hs   = (const float*)d_in[0];
  const float* Wq   = (const float*)d_in[1];
  const float* Wk   = (const float*)d_in[2];
  const float* Wv   = (const float*)d_in[3];
  const float* Wo   = (const float*)d_in[4];
  const float* qw   = (const float*)d_in[5];
  const float* kw   = (const float*)d_in[6];
  const float* gwq  = (const float*)d_in[7];
  const float* gwk  = (const float*)d_in[8];
  const float* cosT = (const float*)d_in[9];
  const float* sinT = (const float*)d_in[10];
  const float* cosG = (const float*)d_in[11];
  const float* sinG = (const float*)d_in[12];
  const float* cosB = (const float*)d_in[13];
  const float* sinB = (const float*)d_in[14];
  float* out = (float*)d_out;
  float* ws = (float*)d_ws;
  const size_t MEG = 1048576;

  // ---- workspace layout (float offsets), lifetime-aliased; total ~75.7 MB ----
  float*          qkvf     = ws;                                 // [0,8M): [T][4096] fp32
  unsigned short* attnb    = (unsigned short*)ws;                //   alias: [0,2M) after qkvf consumed
  float*          pooled   = ws + 2 * MEG;                       //   alias: [2M,3M)
  float*          klsum    = ws + 3 * MEG;                       //   alias: [3M,3M+16K)
  unsigned short* WqkvT    = (unsigned short*)(ws + 8 * MEG);    // [8M,12M): 8M ushorts [4096][2048]
  unsigned short* qbf      = WqkvT;                              //   alias after qkv gemm: 4M ushorts
  unsigned short* kbf      = WqkvT + 4 * MEG;                    //   alias: 2M ushorts
  unsigned short* vt       = WqkvT + 6 * MEG;                    //   alias: 2M ushorts [kv*D][T]
  unsigned short* hsb      = (unsigned short*)(ws + 12 * MEG);   // [12M,14M): 4M ushorts
  float*          knorm    = ws + 12 * MEG;                      //   alias after qkv gemm: 2M floats
  unsigned short* WoT      = (unsigned short*)(ws + 14 * MEG);   // [14M,16M): 4M ushorts
  unsigned short* qpool_bf = (unsigned short*)(ws + 16 * MEG);   // [16M,~16.85M): 1664*8*128 ushorts
  float*          gq       = ws + 17 * MEG;                      // [17M,18.7M): 13312*128 floats
  unsigned short* kblk_bf  = (unsigned short*)(ws + 18 * MEG + 786432);  // 32K ushorts
  float*          gk       = ws + 18 * MEG + 819200;             // 32K floats
  unsigned short* gwqT     = (unsigned short*)(ws + 18 * MEG + 851968);  // 16K ushorts
  unsigned short* gwkT     = (unsigned short*)(ws + 18 * MEG + 860160);  // 16K ushorts

  // casts
  cast_bf16<<<4096, 256, 0, stream>>>(hs, hsb, 1048576);
  castT<<<dim3(32, 32), 256, 0, stream>>>(Wq, WqkvT, HID_, 2048, 2048);
  castT<<<dim3(16, 32), 256, 0, stream>>>(Wk, WqkvT + (size_t)2048 * HID_, HID_, 1024, 1024);
  castT<<<dim3(16, 32), 256, 0, stream>>>(Wv, WqkvT + (size_t)3072 * HID_, HID_, 1024, 1024);
  castT<<<dim3(32, 32), 256, 0, stream>>>(Wo, WoT, 2048, 2048, 2048);
  castT<<<dim3(2, 2), 256, 0, stream>>>(gwq, gwqT, 128, 128, 128);
  castT<<<dim3(2, 2), 256, 0, stream>>>(gwk, gwkT, 128, 128, 128);
  // merged QKV projection: [2048][4096] = hsb @ [Wq|Wk|Wv]
  gemm_bf16_v2<<<dim3(32, 16), 256, 0, stream>>>(hsb, WqkvT, qkvf, 2048, 4096, 2048, 4096);
  // norms + rope (qbf/kbf/vt overwrite WqkvT; knorm overwrites hsb — all dead)
  qnorm_rope_pool<<<dim3(T_, KV_), 128, 0, stream>>>(qkvf, qw, cosT, sinT, qbf, qpool_bf);
  knorm_rope<<<dim3(T_, KV_), 128, 0, stream>>>(qkvf, kw, cosT, sinT, kbf, knorm);
  castT<<<dim3(16, 32), 256, 0, stream>>>(qkvf + 3072, vt, T_, 1024, 4096);  // v -> [d][t] bf16
  kblk_kernel<<<dim3(NB_, KV_), 128, 0, stream>>>(knorm, kblk_bf);
  // gate projections (bf16 MFMA; gq only t>=TG0)
  gemm_bf16_v2<<<dim3(1, 104), 256, 0, stream>>>(qpool_bf, gwqT, gq, 13312, 128, 128, 128);
  gemm_bf16_v2<<<dim3(1, 2), 256, 0, stream>>>(kblk_bf, gwkT, gk, 256, 128, 128, 128);
  rope_g_kernel<<<dim3(T_ - TG0_, KV_), 128, 0, stream>>>(gq, cosG + TG0_ * GH_, sinG + TG0_ * GH_);
  rope_g_kernel<<<dim3(NB_, KV_), 128, 0, stream>>>(gk, cosB, sinB);
  // attention (writes attnb + pooled into dead qkvf region)
  attn_mfma<<<dim3(H_, 32), 256, 0, stream>>>(qbf, kbf, vt, attnb, pooled);
  // output projection
  gemm_bf16_v2<<<dim3(16, 16), 256, 0, stream>>>(attnb, WoT, out, 2048, 2048, 2048, 2048);
  // gate loss
  gate_loss_kernel<<<dim3(KV_, T_ - START_), 64, 0, stream>>>(gq, gk, pooled, klsum);
  finalize_loss<<<1, 256, 0, stream>>>(klsum, out + (size_t)T_ * HID_);
}

// Round 4
// 390.327 us; speedup vs baseline: 6.4732x; 1.0589x over previous
//
#include <hip/hip_runtime.h>

#define T_ 2048
#define HID_ 2048
#define H_ 16
#define KV_ 8
#define G_ 2
#define D_ 128
#define GH_ 128
#define BS_ 64
#define NB_ 32
#define START_ 409
#define TG0_ 384
#define SCALE_ 0.08838834764831845f  // 1/sqrt(128), also 1/sqrt(GH)
#define MFIX_ 8.0f  // fixed softmax max: |logit| <= 128*SCALE = 11.31, exp(11.31-8)=27 safe

typedef __attribute__((ext_vector_type(8))) short short8_t;
typedef __attribute__((ext_vector_type(4))) float float4_t;
typedef __attribute__((ext_vector_type(8))) unsigned short ushort8_t;
typedef __attribute__((ext_vector_type(4))) unsigned short ushort4_t;

// ---------- helpers ----------
__device__ __forceinline__ float wave_sum(float v) {
#pragma unroll
  for (int o = 32; o > 0; o >>= 1) v += __shfl_xor(v, o, 64);
  return v;
}
__device__ __forceinline__ float wave_max(float v) {
#pragma unroll
  for (int o = 32; o > 0; o >>= 1) v = fmaxf(v, __shfl_xor(v, o, 64));
  return v;
}
__device__ __forceinline__ unsigned short f2bf(float x) {
  unsigned int u = __float_as_uint(x);
  unsigned int r = (u + 0x7fffu + ((u >> 16) & 1u)) >> 16;
  return (unsigned short)r;
}

// async global->LDS 16B/lane; LDS dest = wave-uniform base + lane*16
__device__ __forceinline__ void gload16(const void* g, void* l) {
  __builtin_amdgcn_global_load_lds((const __attribute__((address_space(1))) unsigned int*)g,
                                   (__attribute__((address_space(3))) unsigned int*)l, 16, 0, 0);
}

// ---------- cast fp32 -> bf16 (flat, n4 = count/4) ----------
__global__ __launch_bounds__(256) void cast_bf16(const float* __restrict__ in,
                                                 unsigned short* __restrict__ out, int n4) {
  int i = blockIdx.x * 256 + threadIdx.x;
  if (i < n4) {
    float4 v = ((const float4*)in)[i];
    ushort4_t o = {f2bf(v.x), f2bf(v.y), f2bf(v.z), f2bf(v.w)};
    *(ushort4_t*)(out + (size_t)i * 4) = o;
  }
}

// ---------- cast+transpose: out[n][k] = bf16(in[k][n]) ----------
__global__ __launch_bounds__(256) void castT(const float* __restrict__ in,
                                             unsigned short* __restrict__ out,
                                             int K, int N, int ldin) {
  __shared__ unsigned short tile[64][72];
  int k0 = blockIdx.y * 64, n0 = blockIdx.x * 64;
  int tx = threadIdx.x & 63, ty4 = threadIdx.x >> 6;
#pragma unroll
  for (int i = 0; i < 16; ++i) {
    int ky = ty4 * 16 + i;
    tile[tx][ky] = f2bf(in[(size_t)(k0 + ky) * ldin + n0 + tx]);
  }
  __syncthreads();
#pragma unroll
  for (int i = 0; i < 16; ++i) {
    int ny = ty4 * 16 + i;
    out[(size_t)(n0 + ny) * K + k0 + tx] = tile[ny][tx];
  }
}

// ---------- bf16 MFMA GEMM (m97-style): C fp32[M][ldc] = A bf16[M][K] @ Bt bf16[N][K] ----------
__global__ __launch_bounds__(256) void gemm_bf16_v2(const unsigned short* __restrict__ A,
                                                    const unsigned short* __restrict__ Bt,
                                                    float* __restrict__ C,
                                                    int M, int N, int K, int ldc) {
  __shared__ unsigned short As[128 * 32];
  __shared__ unsigned short Bs[128 * 32];
  int tid = threadIdx.x;
  int wid = tid >> 6, lane = tid & 63;
  int quad = lane >> 4, l16 = lane & 15;
  int wm = wid & 1, wn = wid >> 1;
  int m0 = blockIdx.y * 128, n0 = blockIdx.x * 128;
  int e0 = wid * 512 + lane * 8;
  int r0 = e0 >> 5, c0 = e0 & 31;
  const unsigned short* ga0 = A + (size_t)(m0 + r0) * K + c0;
  const unsigned short* ga1 = A + (size_t)(m0 + r0 + 64) * K + c0;
  const unsigned short* gb0 = Bt + (size_t)(n0 + r0) * K + c0;
  const unsigned short* gb1 = Bt + (size_t)(n0 + r0 + 64) * K + c0;
  unsigned short* lA0 = As + wid * 512;
  unsigned short* lA1 = As + 2048 + wid * 512;
  unsigned short* lB0 = Bs + wid * 512;
  unsigned short* lB1 = Bs + 2048 + wid * 512;
  float4_t acc[4][4];
#pragma unroll
  for (int i = 0; i < 4; ++i)
#pragma unroll
    for (int j = 0; j < 4; ++j) acc[i][j] = (float4_t){0.f, 0.f, 0.f, 0.f};
  for (int k0 = 0; k0 < K; k0 += 32) {
    __syncthreads();
    gload16(ga0 + k0, lA0);
    gload16(ga1 + k0, lA1);
    gload16(gb0 + k0, lB0);
    gload16(gb1 + k0, lB1);
    __syncthreads();
    short8_t a[4], b[4];
#pragma unroll
    for (int i = 0; i < 4; ++i)
      a[i] = *(const short8_t*)&As[(wm * 64 + i * 16 + l16) * 32 + quad * 8];
#pragma unroll
    for (int j = 0; j < 4; ++j)
      b[j] = *(const short8_t*)&Bs[(wn * 64 + j * 16 + l16) * 32 + quad * 8];
#pragma unroll
    for (int i = 0; i < 4; ++i)
#pragma unroll
      for (int j = 0; j < 4; ++j)
        acc[i][j] = __builtin_amdgcn_mfma_f32_16x16x32_bf16(a[i], b[j], acc[i][j], 0, 0, 0);
  }
#pragma unroll
  for (int i = 0; i < 4; ++i)
#pragma unroll
    for (int j = 0; j < 4; ++j)
#pragma unroll
      for (int reg = 0; reg < 4; ++reg)
        C[(size_t)(m0 + wm * 64 + i * 16 + quad * 4 + reg) * ldc + n0 + wn * 64 + j * 16 + l16] =
            acc[i][j][reg];
}

// ---------- fused q/k rmsnorm + rope (+q pool); grid (T, 16): y<8 q-pair, y>=8 k ----------
__global__ __launch_bounds__(128) void norm_rope_fused(const float* __restrict__ qkvf,
                                                       const float* __restrict__ qw,
                                                       const float* __restrict__ kw,
                                                       const float* __restrict__ cosT,
                                                       const float* __restrict__ sinT,
                                                       unsigned short* __restrict__ qbf,
                                                       unsigned short* __restrict__ qpool_bf,
                                                       unsigned short* __restrict__ kbf,
                                                       float* __restrict__ knorm) {
  int t = blockIdx.x, d = threadIdx.x;
  if (blockIdx.y < 8) {
    int kv = blockIdx.y;
    size_t i0 = (size_t)t * 4096 + (kv * G_) * D_ + d;
    float x0 = qkvf[i0], x1 = qkvf[i0 + D_];
    __shared__ float sred[2][2];
    float s0 = wave_sum(x0 * x0), s1 = wave_sum(x1 * x1);
    if ((d & 63) == 0) { sred[0][d >> 6] = s0; sred[1][d >> 6] = s1; }
    __syncthreads();
    float wv = qw[d];
    float n0 = x0 * rsqrtf((sred[0][0] + sred[0][1]) * (1.f / D_) + 1e-6f) * wv;
    float n1 = x1 * rsqrtf((sred[1][0] + sred[1][1]) * (1.f / D_) + 1e-6f) * wv;
    if (t >= TG0_) qpool_bf[((size_t)(t - TG0_) * KV_ + kv) * D_ + d] = f2bf(0.5f * (n0 + n1));
    __shared__ float sh[2][D_];
    sh[0][d] = n0; sh[1][d] = n1;
    __syncthreads();
    float c = cosT[t * D_ + d], s = sinT[t * D_ + d];
    float r0 = (d < 64) ? -sh[0][d + 64] : sh[0][d - 64];
    float r1 = (d < 64) ? -sh[1][d + 64] : sh[1][d - 64];
    qbf[((size_t)(t * H_) + kv * G_) * D_ + d] = f2bf(n0 * c + r0 * s);
    qbf[((size_t)(t * H_) + kv * G_ + 1) * D_ + d] = f2bf(n1 * c + r1 * s);
  } else {
    int kv = blockIdx.y - 8;
    float x = qkvf[(size_t)t * 4096 + 2048 + kv * D_ + d];
    __shared__ float sredk[2];
    float s0 = wave_sum(x * x);
    if ((d & 63) == 0) sredk[d >> 6] = s0;
    __syncthreads();
    float nk = x * rsqrtf((sredk[0] + sredk[1]) * (1.f / D_) + 1e-6f) * kw[d];
    knorm[(size_t)(t * KV_ + kv) * D_ + d] = nk;
    __shared__ float shk[D_];
    shk[d] = nk;
    __syncthreads();
    float rot = (d < 64) ? -shk[d + 64] : shk[d - 64];
    kbf[(size_t)(t * KV_ + kv) * D_ + d] = f2bf(nk * cosT[t * D_ + d] + rot * sinT[t * D_ + d]);
  }
}

// ---------- k_blk = mean over BS rows of knorm -> bf16 ----------
__global__ __launch_bounds__(128) void kblk_kernel(const float* __restrict__ knorm,
                                                   unsigned short* __restrict__ kblk_bf) {
  int n = blockIdx.x, kv = blockIdx.y, d = threadIdx.x;
  float s = 0.f;
  for (int i = 0; i < BS_; ++i) s += knorm[((size_t)(n * BS_ + i) * KV_ + kv) * D_ + d];
  kblk_bf[(size_t)(n * KV_ + kv) * D_ + d] = f2bf(s * (1.f / BS_));
}

// ---------- fused rope for gk (rows<NB) and gq (rows>=NB, table offset TG0) ----------
__global__ __launch_bounds__(128) void rope_g_fused(float* __restrict__ gq, float* __restrict__ gk,
                                                    const float* __restrict__ cosG,
                                                    const float* __restrict__ sinG,
                                                    const float* __restrict__ cosB,
                                                    const float* __restrict__ sinB) {
  int r = blockIdx.x, kvh = blockIdx.y, d = threadIdx.x;
  float* x;
  size_t base;
  float c_, s_;
  if (r < NB_) {
    x = gk;
    base = (size_t)(r * KV_ + kvh) * GH_;
    c_ = cosB[r * GH_ + d]; s_ = sinB[r * GH_ + d];
  } else {
    int rr = r - NB_;
    x = gq;
    base = (size_t)(rr * KV_ + kvh) * GH_;
    c_ = cosG[(size_t)(TG0_ + rr) * GH_ + d]; s_ = sinG[(size_t)(TG0_ + rr) * GH_ + d];
  }
  __shared__ float sh[GH_];
  sh[d] = x[base + d];
  __syncthreads();
  float rot = (d < 64) ? -sh[d + 64] : sh[d - 64];
  x[base + d] = sh[d] * c_ + rot * s_;
}

// ---------- MFMA flash attention, fixed-max softmax ----------
// grid (H, 32) with tile remap; 256 thr = 4 waves x 16 q-rows; chunk = 64 keys
// Staging: global_load_lds w/ source-side XOR swizzle (unpadded LDS, balanced frag reads).
// Row sums (l + pooled) via MFMA against all-ones B fragment — no shuffle reductions.
__global__ __launch_bounds__(256) void attn_mfma(const unsigned short* __restrict__ qbf,
                                                 const unsigned short* __restrict__ kbf,
                                                 const unsigned short* __restrict__ vt,
                                                 unsigned short* __restrict__ attnb,
                                                 float* __restrict__ pooled) {
  int h = blockIdx.x;
  int yy = blockIdx.y;
  int tile = (yy < 16) ? yy : 47 - yy;
  int t0 = tile * 64;
  int tid = threadIdx.x;
  int wid = tid >> 6, lane = tid & 63;
  int quad = lane >> 4, l16 = lane & 15;
  int kv = h >> 1;
  __shared__ unsigned short Ks[64 * 128];   // [key][16B-chunk ^ (key&7)]
  __shared__ unsigned short Vs[128 * 64];   // [d][16B-chunk ^ (d&7)]
  __shared__ unsigned short Ps[4][16 * 72];

  // staging source pointers (per lane), 4 K segs + 4 V segs per wave
  const unsigned short* kbase[4];
  const unsigned short* vbase[4];
#pragma unroll
  for (int it = 0; it < 4; ++it) {
    int seg = wid * 4 + it;
    int krow = seg * 4 + (lane >> 4);
    int kchk = lane & 15;
    kbase[it] = kbf + ((size_t)krow * KV_ + kv) * D_ + ((kchk ^ (krow & 7)) << 3);
    int vrow = seg * 8 + (lane >> 3);
    int vchk = lane & 7;
    vbase[it] = vt + (size_t)(kv * 128 + vrow) * T_ + ((vchk ^ (vrow & 7)) << 3);
  }

  // Q fragments in regs
  int tq = t0 + wid * 16 + l16;
  short8_t qf[4];
#pragma unroll
  for (int kb = 0; kb < 4; ++kb)
    qf[kb] = *(const short8_t*)&qbf[((size_t)tq * H_ + h) * D_ + kb * 32 + quad * 8];

  const short one_bf = (short)0x3F80;
  short8_t ones = {one_bf, one_bf, one_bf, one_bf, one_bf, one_bf, one_bf, one_bf};

  int tbase = t0 + wid * 16 + quad * 4;
  float l_[4] = {0.f, 0.f, 0.f, 0.f};
  float pacc[2][4] = {};
  float4_t o[8];
#pragma unroll
  for (int j = 0; j < 8; ++j) o[j] = (float4_t){0.f, 0.f, 0.f, 0.f};

  int nchunks = tile + 1;
  for (int c = 0; c < nchunks; ++c) {
    __syncthreads();
#pragma unroll
    for (int it = 0; it < 4; ++it) {
      gload16(kbase[it] + (size_t)c * 65536, Ks + (wid * 4 + it) * 512);
      gload16(vbase[it] + c * 64, Vs + (wid * 4 + it) * 512);
    }
    __syncthreads();

    // ---- QK^T: S 16x64 per wave ----
    float4_t s[4];
#pragma unroll
    for (int j = 0; j < 4; ++j) {
      float4_t a = (float4_t){0.f, 0.f, 0.f, 0.f};
#pragma unroll
      for (int kb = 0; kb < 4; ++kb) {
        short8_t kf = *(const short8_t*)&Ks[(j * 16 + l16) * 128 + (((kb * 4 + quad) ^ (l16 & 7)) << 3)];
        a = __builtin_amdgcn_mfma_f32_16x16x32_bf16(qf[kb], kf, a, 0, 0, 0);
      }
      s[j] = a;
    }
    // ---- p = exp(logit - MFIX); mask only on diagonal chunk ----
    if (c == tile) {
#pragma unroll
      for (int reg = 0; reg < 4; ++reg) {
        int trow = tbase + reg;
#pragma unroll
        for (int j = 0; j < 4; ++j) {
          float p = __expf(s[j][reg] * SCALE_ - MFIX_);
          s[j][reg] = (c * 64 + j * 16 + l16 <= trow) ? p : 0.f;
        }
      }
    } else {
#pragma unroll
      for (int j = 0; j < 4; ++j)
#pragma unroll
        for (int reg = 0; reg < 4; ++reg)
          s[j][reg] = __expf(s[j][reg] * SCALE_ - MFIX_);
    }
    // write P (C layout) -> per-wave LDS [r][s]
#pragma unroll
    for (int j = 0; j < 4; ++j)
#pragma unroll
      for (int reg = 0; reg < 4; ++reg)
        Ps[wid][(quad * 4 + reg) * 72 + j * 16 + l16] = f2bf(s[j][reg]);
    // ---- PV + row-sum-via-ones ----
    float4_t pool = (float4_t){0.f, 0.f, 0.f, 0.f};
#pragma unroll
    for (int ks = 0; ks < 2; ++ks) {
      short8_t pf = *(const short8_t*)&Ps[wid][l16 * 72 + ks * 32 + quad * 8];
      pool = __builtin_amdgcn_mfma_f32_16x16x32_bf16(pf, ones, pool, 0, 0, 0);
#pragma unroll
      for (int jt = 0; jt < 8; ++jt) {
        short8_t vf = *(const short8_t*)&Vs[(jt * 16 + l16) * 64 + (((ks * 4 + quad) ^ (l16 & 7)) << 3)];
        o[jt] = __builtin_amdgcn_mfma_f32_16x16x32_bf16(pf, vf, o[jt], 0, 0, 0);
      }
    }
    int half = c >> 4, cl = c & 15;
#pragma unroll
    for (int reg = 0; reg < 4; ++reg) {
      l_[reg] += pool[reg];
      if (l16 == cl) pacc[half][reg] = pool[reg];
    }
  }
  // epilogue
  float inv[4];
#pragma unroll
  for (int reg = 0; reg < 4; ++reg) inv[reg] = 1.f / l_[reg];
#pragma unroll
  for (int jt = 0; jt < 8; ++jt)
#pragma unroll
    for (int reg = 0; reg < 4; ++reg)
      attnb[(size_t)(tbase + reg) * (H_ * D_) + h * D_ + jt * 16 + l16] =
          f2bf(o[jt][reg] * inv[reg]);
#pragma unroll
  for (int reg = 0; reg < 4; ++reg) {
    int trow = tbase + reg;
    pooled[((size_t)h * T_ + trow) * NB_ + l16] = pacc[0][reg] * inv[reg];
    pooled[((size_t)h * T_ + trow) * NB_ + 16 + l16] = pacc[1][reg] * inv[reg];
  }
}

// ---------- gate loss ----------
__global__ __launch_bounds__(64) void gate_loss_kernel(const float* __restrict__ gq,
                                                       const float* __restrict__ gk,
                                                       const float* __restrict__ pooled,
                                                       float* __restrict__ klsum) {
  int kv = blockIdx.x;
  int t = START_ + blockIdx.y;
  int n = threadIdx.x;
  float dot = 0.f;
  if (n < NB_) {
    const float* a = gq + ((size_t)(t - TG0_) * KV_ + kv) * GH_;
    const float* b = gk + (size_t)(n * KV_ + kv) * GH_;
    for (int d = 0; d < GH_; ++d) dot += a[d] * b[d];
  }
  bool valid = (n < NB_) && ((t / BS_) >= n);
  float score = valid ? dot * SCALE_ : -1e9f;
  float M = wave_max(score);
  float Z = wave_sum(__expf(score - M));
  float logZ = M + logf(Z);
  float g = 0.f;
  if (valid) {
    float p0 = pooled[((size_t)(kv * G_) * T_ + t) * NB_ + n];
    float p1 = pooled[((size_t)(kv * G_ + 1) * T_ + t) * NB_ + n];
    g = fmaxf(p0, p1);
  }
  float gs = wave_sum(g);
  float tgt = g / (gs + 1e-9f);
  float kl = (tgt > 0.f) ? tgt * (logf(tgt) - (score - logZ)) : 0.f;
  float ks = wave_sum(kl);
  if (n == 0) klsum[kv * (T_ - START_) + blockIdx.y] = ks;
}

__global__ __launch_bounds__(256) void finalize_loss(const float* __restrict__ klsum,
                                                     float* __restrict__ out) {
  const int n = KV_ * (T_ - START_);
  float s = 0.f;
  for (int i = threadIdx.x; i < n; i += 256) s += klsum[i];
  s = wave_sum(s);
  __shared__ float sh[4];
  if ((threadIdx.x & 63) == 0) sh[threadIdx.x >> 6] = s;
  __syncthreads();
  if (threadIdx.x == 0)
    out[0] = (sh[0] + sh[1] + sh[2] + sh[3]) * (1.f / ((float)(T_ - START_) * NB_));
}

extern "C" void kernel_launch(void* const* d_in, const int* in_sizes, int n_in,
                              void* d_out, int out_size, void* d_ws, size_t ws_size,
                              hipStream_t stream) {
  const float* hs   = (const float*)d_in[0];
  const float* Wq   = (const float*)d_in[1];
  const float* Wk   = (const float*)d_in[2];
  const float* Wv   = (const float*)d_in[3];
  const float* Wo   = (const float*)d_in[4];
  const float* qw   = (const float*)d_in[5];
  const float* kw   = (const float*)d_in[6];
  const float* gwq  = (const float*)d_in[7];
  const float* gwk  = (const float*)d_in[8];
  const float* cosT = (const float*)d_in[9];
  const float* sinT = (const float*)d_in[10];
  const float* cosG = (const float*)d_in[11];
  const float* sinG = (const float*)d_in[12];
  const float* cosB = (const float*)d_in[13];
  const float* sinB = (const float*)d_in[14];
  float* out = (float*)d_out;
  float* ws = (float*)d_ws;
  const size_t MEG = 1048576;

  // ---- workspace layout (float offsets), lifetime-aliased ----
  float*          qkvf     = ws;                                 // [0,8M): [T][4096] fp32
  unsigned short* attnb    = (unsigned short*)ws;                //   alias after qkvf consumed
  float*          pooled   = ws + 2 * MEG;                       //   alias
  float*          klsum    = ws + 3 * MEG;                       //   alias
  unsigned short* WqkvT    = (unsigned short*)(ws + 8 * MEG);    // [8M,12M): 8M ushorts
  unsigned short* qbf      = WqkvT;                              //   alias after qkv gemm
  unsigned short* kbf      = WqkvT + 4 * MEG;
  unsigned short* vt       = WqkvT + 6 * MEG;
  unsigned short* hsb      = (unsigned short*)(ws + 12 * MEG);   // [12M,14M)
  float*          knorm    = ws + 12 * MEG;                      //   alias after qkv gemm
  unsigned short* WoT      = (unsigned short*)(ws + 14 * MEG);   // [14M,16M)
  unsigned short* qpool_bf = (unsigned short*)(ws + 16 * MEG);   // [16M,...)
  float*          gq       = ws + 17 * MEG;
  unsigned short* kblk_bf  = (unsigned short*)(ws + 18 * MEG + 786432);
  float*          gk       = ws + 18 * MEG + 819200;
  unsigned short* gwqT     = (unsigned short*)(ws + 18 * MEG + 851968);
  unsigned short* gwkT     = (unsigned short*)(ws + 18 * MEG + 860160);

  cast_bf16<<<4096, 256, 0, stream>>>(hs, hsb, 1048576);
  castT<<<dim3(32, 32), 256, 0, stream>>>(Wq, WqkvT, HID_, 2048, 2048);
  castT<<<dim3(16, 32), 256, 0, stream>>>(Wk, WqkvT + (size_t)2048 * HID_, HID_, 1024, 1024);
  castT<<<dim3(16, 32), 256, 0, stream>>>(Wv, WqkvT + (size_t)3072 * HID_, HID_, 1024, 1024);
  castT<<<dim3(32, 32), 256, 0, stream>>>(Wo, WoT, 2048, 2048, 2048);
  castT<<<dim3(2, 2), 256, 0, stream>>>(gwq, gwqT, 128, 128, 128);
  castT<<<dim3(2, 2), 256, 0, stream>>>(gwk, gwkT, 128, 128, 128);
  gemm_bf16_v2<<<dim3(32, 16), 256, 0, stream>>>(hsb, WqkvT, qkvf, 2048, 4096, 2048, 4096);
  norm_rope_fused<<<dim3(T_, 16), 128, 0, stream>>>(qkvf, qw, kw, cosT, sinT, qbf, qpool_bf,
                                                    kbf, knorm);
  castT<<<dim3(16, 32), 256, 0, stream>>>(qkvf + 3072, vt, T_, 1024, 4096);
  kblk_kernel<<<dim3(NB_, KV_), 128, 0, stream>>>(knorm, kblk_bf);
  gemm_bf16_v2<<<dim3(1, 104), 256, 0, stream>>>(qpool_bf, gwqT, gq, 13312, 128, 128, 128);
  gemm_bf16_v2<<<dim3(1, 2), 256, 0, stream>>>(kblk_bf, gwkT, gk, 256, 128, 128, 128);
  rope_g_fused<<<dim3(NB_ + (T_ - TG0_), KV_), 128, 0, stream>>>(gq, gk, cosG, sinG, cosB, sinB);
  attn_mfma<<<dim3(H_, 32), 256, 0, stream>>>(qbf, kbf, vt, attnb, pooled);
  gemm_bf16_v2<<<dim3(16, 16), 256, 0, stream>>>(attnb, WoT, out, 2048, 2048, 2048, 2048);
  gate_loss_kernel<<<dim3(KV_, T_ - START_), 64, 0, stream>>>(gq, gk, pooled, klsum);
  finalize_loss<<<1, 256, 0, stream>>>(klsum, out + (size_t)T_ * HID_);
}

// Round 5
// 361.632 us; speedup vs baseline: 6.9868x; 1.0793x over previous
//
#include <hip/hip_runtime.h>

#define T_ 2048
#define HID_ 2048
#define H_ 16
#define KV_ 8
#define G_ 2
#define D_ 128
#define GH_ 128
#define BS_ 64
#define NB_ 32
#define START_ 409
#define TG0_ 384
#define SCALE_ 0.08838834764831845f  // 1/sqrt(128), also 1/sqrt(GH)
#define MFIX_ 8.0f  // fixed softmax max: |logit| <= 128*SCALE = 11.31 (q,k rmsnormed)

typedef __attribute__((ext_vector_type(8))) short short8_t;
typedef __attribute__((ext_vector_type(4))) float float4_t;
typedef __attribute__((ext_vector_type(8))) unsigned short ushort8_t;
typedef __attribute__((ext_vector_type(4))) unsigned short ushort4_t;

// ---------- helpers ----------
__device__ __forceinline__ float wave_sum(float v) {
#pragma unroll
  for (int o = 32; o > 0; o >>= 1) v += __shfl_xor(v, o, 64);
  return v;
}
__device__ __forceinline__ unsigned short f2bf(float x) {
  unsigned int u = __float_as_uint(x);
  unsigned int r = (u + 0x7fffu + ((u >> 16) & 1u)) >> 16;
  return (unsigned short)r;
}

// async global->LDS 16B/lane; LDS dest = wave-uniform base + lane*16
__device__ __forceinline__ void gload16(const void* g, void* l) {
  __builtin_amdgcn_global_load_lds((const __attribute__((address_space(1))) unsigned int*)g,
                                   (__attribute__((address_space(3))) unsigned int*)l, 16, 0, 0);
}

// ---------- 64x64 cast+transpose tile (device) ----------
__device__ __forceinline__ void castT_dev(const float* __restrict__ in,
                                          unsigned short* __restrict__ out, int K, int N,
                                          int ldin, int bx, int by,
                                          unsigned short (*tile)[72], int tid) {
  int k0 = by * 64, n0 = bx * 64;
  int tx = tid & 63, ty4 = tid >> 6;
#pragma unroll
  for (int i = 0; i < 16; ++i) {
    int ky = ty4 * 16 + i;
    tile[tx][ky] = f2bf(in[(size_t)(k0 + ky) * ldin + n0 + tx]);
  }
  __syncthreads();
#pragma unroll
  for (int i = 0; i < 16; ++i) {
    int ny = ty4 * 16 + i;
    out[(size_t)(n0 + ny) * K + k0 + tx] = tile[ny][tx];
  }
}

// ---------- standalone castT (for v after QKV gemm) ----------
__global__ __launch_bounds__(256) void castT(const float* __restrict__ in,
                                             unsigned short* __restrict__ out,
                                             int K, int N, int ldin) {
  __shared__ unsigned short tile[64][72];
  castT_dev(in, out, K, N, ldin, blockIdx.x, blockIdx.y, tile, threadIdx.x);
}

// ---------- fused prologue: hs cast + all weight cast-transposes in one launch ----------
__global__ __launch_bounds__(256) void prep_cast(const float* __restrict__ hs,
                                                 const float* __restrict__ Wq,
                                                 const float* __restrict__ Wk,
                                                 const float* __restrict__ Wv,
                                                 const float* __restrict__ Wo,
                                                 const float* __restrict__ gwq,
                                                 const float* __restrict__ gwk,
                                                 unsigned short* __restrict__ hsb,
                                                 unsigned short* __restrict__ WqkvT,
                                                 unsigned short* __restrict__ WoT,
                                                 unsigned short* __restrict__ gwqT,
                                                 unsigned short* __restrict__ gwkT) {
  __shared__ unsigned short tile[64][72];
  int id = blockIdx.x, tid = threadIdx.x;
  if (id < 4096) {  // hs -> bf16 flat (4096*256 = 1048576 float4s)
    int i = id * 256 + tid;
    float4 v = ((const float4*)hs)[i];
    ushort4_t o = {f2bf(v.x), f2bf(v.y), f2bf(v.z), f2bf(v.w)};
    *(ushort4_t*)(hsb + (size_t)i * 4) = o;
  } else if (id < 5120) {  // Wq: 32x32 tiles
    int t = id - 4096;
    castT_dev(Wq, WqkvT, 2048, 2048, 2048, t & 31, t >> 5, tile, tid);
  } else if (id < 5632) {  // Wk: 16x32
    int t = id - 5120;
    castT_dev(Wk, WqkvT + (size_t)2048 * 2048, 2048, 1024, 1024, t & 15, t >> 4, tile, tid);
  } else if (id < 6144) {  // Wv: 16x32
    int t = id - 5632;
    castT_dev(Wv, WqkvT + (size_t)3072 * 2048, 2048, 1024, 1024, t & 15, t >> 4, tile, tid);
  } else if (id < 7168) {  // Wo: 32x32
    int t = id - 6144;
    castT_dev(Wo, WoT, 2048, 2048, 2048, t & 31, t >> 5, tile, tid);
  } else if (id < 7172) {  // gwq: 2x2
    int t = id - 7168;
    castT_dev(gwq, gwqT, 128, 128, 128, t & 1, t >> 1, tile, tid);
  } else {  // gwk: 2x2
    int t = id - 7172;
    castT_dev(gwk, gwkT, 128, 128, 128, t & 1, t >> 1, tile, tid);
  }
}

// ---------- bf16 MFMA GEMM v3: BK=64, swizzled conflict-free LDS ----------
// C fp32[M][ldc] = A bf16[M][K] @ Bt bf16[N][K]; tile 128x128, 4 waves (2x2 of 64x64)
// LDS layout: row r (128B line) holds chunk c (16B) at slot c ^ (r&7) -> frag reads 2-way max.
__global__ __launch_bounds__(256) void gemm_bf16_v3(const unsigned short* __restrict__ A,
                                                    const unsigned short* __restrict__ Bt,
                                                    float* __restrict__ C,
                                                    int M, int N, int K, int ldc) {
  __shared__ unsigned short As[128 * 64];
  __shared__ unsigned short Bs[128 * 64];
  int tid = threadIdx.x;
  int wid = tid >> 6, lane = tid & 63;
  int quad = lane >> 4, l16 = lane & 15;
  int wm = wid & 1, wn = wid >> 1;
  int m0 = blockIdx.y * 128, n0 = blockIdx.x * 128;
  // staging: per wave 32 rows per array, 4 segments of 8 lines (128B each)
  const unsigned short* gA[4];
  const unsigned short* gB[4];
#pragma unroll
  for (int it = 0; it < 4; ++it) {
    int line = wid * 32 + it * 8 + (lane >> 3);
    int chunk = (lane & 7) ^ (line & 7);
    gA[it] = A + (size_t)(m0 + line) * K + chunk * 8;
    gB[it] = Bt + (size_t)(n0 + line) * K + chunk * 8;
  }
  float4_t acc[4][4];
#pragma unroll
  for (int i = 0; i < 4; ++i)
#pragma unroll
    for (int j = 0; j < 4; ++j) acc[i][j] = (float4_t){0.f, 0.f, 0.f, 0.f};
  for (int k0 = 0; k0 < K; k0 += 64) {
    __syncthreads();
#pragma unroll
    for (int it = 0; it < 4; ++it) {
      gload16(gA[it] + k0, As + (wid * 32 + it * 8) * 64);
      gload16(gB[it] + k0, Bs + (wid * 32 + it * 8) * 64);
    }
    __syncthreads();
    short8_t a[2][4], b[2][4];
#pragma unroll
    for (int ks = 0; ks < 2; ++ks) {
      int sw = ((ks * 4 + quad) ^ (l16 & 7)) * 8;
#pragma unroll
      for (int i = 0; i < 4; ++i) {
        a[ks][i] = *(const short8_t*)&As[(wm * 64 + i * 16 + l16) * 64 + sw];
        b[ks][i] = *(const short8_t*)&Bs[(wn * 64 + i * 16 + l16) * 64 + sw];
      }
    }
#pragma unroll
    for (int ks = 0; ks < 2; ++ks)
#pragma unroll
      for (int i = 0; i < 4; ++i)
#pragma unroll
        for (int j = 0; j < 4; ++j)
          acc[i][j] = __builtin_amdgcn_mfma_f32_16x16x32_bf16(a[ks][i], b[ks][j], acc[i][j], 0, 0, 0);
  }
#pragma unroll
  for (int i = 0; i < 4; ++i)
#pragma unroll
    for (int j = 0; j < 4; ++j)
#pragma unroll
      for (int reg = 0; reg < 4; ++reg)
        C[(size_t)(m0 + wm * 64 + i * 16 + quad * 4 + reg) * ldc + n0 + wn * 64 + j * 16 + l16] =
            acc[i][j][reg];
}

// ---------- fused q/k rmsnorm + rope (+q pool); grid (T, 16): y<8 q-pair, y>=8 k ----------
__global__ __launch_bounds__(128) void norm_rope_fused(const float* __restrict__ qkvf,
                                                       const float* __restrict__ qw,
                                                       const float* __restrict__ kw,
                                                       const float* __restrict__ cosT,
                                                       const float* __restrict__ sinT,
                                                       unsigned short* __restrict__ qbf,
                                                       unsigned short* __restrict__ qpool_bf,
                                                       unsigned short* __restrict__ kbf,
                                                       float* __restrict__ knorm) {
  int t = blockIdx.x, d = threadIdx.x;
  if (blockIdx.y < 8) {
    int kv = blockIdx.y;
    size_t i0 = (size_t)t * 4096 + (kv * G_) * D_ + d;
    float x0 = qkvf[i0], x1 = qkvf[i0 + D_];
    __shared__ float sred[2][2];
    float s0 = wave_sum(x0 * x0), s1 = wave_sum(x1 * x1);
    if ((d & 63) == 0) { sred[0][d >> 6] = s0; sred[1][d >> 6] = s1; }
    __syncthreads();
    float wv = qw[d];
    float n0 = x0 * rsqrtf((sred[0][0] + sred[0][1]) * (1.f / D_) + 1e-6f) * wv;
    float n1 = x1 * rsqrtf((sred[1][0] + sred[1][1]) * (1.f / D_) + 1e-6f) * wv;
    if (t >= TG0_) qpool_bf[((size_t)(t - TG0_) * KV_ + kv) * D_ + d] = f2bf(0.5f * (n0 + n1));
    __shared__ float sh[2][D_];
    sh[0][d] = n0; sh[1][d] = n1;
    __syncthreads();
    float c = cosT[t * D_ + d], s = sinT[t * D_ + d];
    float r0 = (d < 64) ? -sh[0][d + 64] : sh[0][d - 64];
    float r1 = (d < 64) ? -sh[1][d + 64] : sh[1][d - 64];
    qbf[((size_t)(t * H_) + kv * G_) * D_ + d] = f2bf(n0 * c + r0 * s);
    qbf[((size_t)(t * H_) + kv * G_ + 1) * D_ + d] = f2bf(n1 * c + r1 * s);
  } else {
    int kv = blockIdx.y - 8;
    float x = qkvf[(size_t)t * 4096 + 2048 + kv * D_ + d];
    __shared__ float sredk[2];
    float s0 = wave_sum(x * x);
    if ((d & 63) == 0) sredk[d >> 6] = s0;
    __syncthreads();
    float nk = x * rsqrtf((sredk[0] + sredk[1]) * (1.f / D_) + 1e-6f) * kw[d];
    knorm[(size_t)(t * KV_ + kv) * D_ + d] = nk;
    __shared__ float shk[D_];
    shk[d] = nk;
    __syncthreads();
    float rot = (d < 64) ? -shk[d + 64] : shk[d - 64];
    kbf[(size_t)(t * KV_ + kv) * D_ + d] = f2bf(nk * cosT[t * D_ + d] + rot * sinT[t * D_ + d]);
  }
}

// ---------- k_blk = mean over BS rows of knorm -> bf16 ----------
__global__ __launch_bounds__(128) void kblk_kernel(const float* __restrict__ knorm,
                                                   unsigned short* __restrict__ kblk_bf) {
  int n = blockIdx.x, kv = blockIdx.y, d = threadIdx.x;
  float s = 0.f;
  for (int i = 0; i < BS_; ++i) s += knorm[((size_t)(n * BS_ + i) * KV_ + kv) * D_ + d];
  kblk_bf[(size_t)(n * KV_ + kv) * D_ + d] = f2bf(s * (1.f / BS_));
}

// ---------- fused rope for gk (rows<NB) and gq (rows>=NB, table offset TG0) ----------
__global__ __launch_bounds__(128) void rope_g_fused(float* __restrict__ gq, float* __restrict__ gk,
                                                    const float* __restrict__ cosG,
                                                    const float* __restrict__ sinG,
                                                    const float* __restrict__ cosB,
                                                    const float* __restrict__ sinB) {
  int r = blockIdx.x, kvh = blockIdx.y, d = threadIdx.x;
  float* x;
  size_t base;
  float c_, s_;
  if (r < NB_) {
    x = gk;
    base = (size_t)(r * KV_ + kvh) * GH_;
    c_ = cosB[r * GH_ + d]; s_ = sinB[r * GH_ + d];
  } else {
    int rr = r - NB_;
    x = gq;
    base = (size_t)(rr * KV_ + kvh) * GH_;
    c_ = cosG[(size_t)(TG0_ + rr) * GH_ + d]; s_ = sinG[(size_t)(TG0_ + rr) * GH_ + d];
  }
  __shared__ float sh[GH_];
  sh[d] = x[base + d];
  __syncthreads();
  float rot = (d < 64) ? -sh[d + 64] : sh[d - 64];
  x[base + d] = sh[d] * c_ + rot * s_;
}

// ---------- MFMA flash attention: fixed-max softmax + double-buffered staging ----------
__global__ __launch_bounds__(256) void attn_mfma(const unsigned short* __restrict__ qbf,
                                                 const unsigned short* __restrict__ kbf,
                                                 const unsigned short* __restrict__ vt,
                                                 unsigned short* __restrict__ attnb,
                                                 float* __restrict__ pooled) {
  int h = blockIdx.x;
  int yy = blockIdx.y;
  int tile = (yy < 16) ? yy : 47 - yy;
  int t0 = tile * 64;
  int tid = threadIdx.x;
  int wid = tid >> 6, lane = tid & 63;
  int quad = lane >> 4, l16 = lane & 15;
  int kv = h >> 1;
  __shared__ unsigned short Ks[2][64 * 128];   // [key][chunk16 ^ (key&7)]
  __shared__ unsigned short Vs[2][128 * 64];   // [d][chunk16 ^ (d&7)]
  __shared__ unsigned short Ps[4][16 * 72];

  const unsigned short* kbase[4];
  const unsigned short* vbase[4];
#pragma unroll
  for (int it = 0; it < 4; ++it) {
    int seg = wid * 4 + it;
    int krow = seg * 4 + (lane >> 4);
    int kchk = lane & 15;
    kbase[it] = kbf + ((size_t)krow * KV_ + kv) * D_ + ((kchk ^ (krow & 7)) << 3);
    int vrow = seg * 8 + (lane >> 3);
    int vchk = lane & 7;
    vbase[it] = vt + (size_t)(kv * 128 + vrow) * T_ + ((vchk ^ (vrow & 7)) << 3);
  }

  int tq = t0 + wid * 16 + l16;
  short8_t qf[4];
#pragma unroll
  for (int kb = 0; kb < 4; ++kb)
    qf[kb] = *(const short8_t*)&qbf[((size_t)tq * H_ + h) * D_ + kb * 32 + quad * 8];

  const short one_bf = (short)0x3F80;
  short8_t ones = {one_bf, one_bf, one_bf, one_bf, one_bf, one_bf, one_bf, one_bf};

  int tbase = t0 + wid * 16 + quad * 4;
  float l_[4] = {0.f, 0.f, 0.f, 0.f};
  float pacc[2][4] = {};
  float4_t o[8];
#pragma unroll
  for (int j = 0; j < 8; ++j) o[j] = (float4_t){0.f, 0.f, 0.f, 0.f};

  int nchunks = tile + 1;
  // prologue: stage chunk 0 into buffer 0
#pragma unroll
  for (int it = 0; it < 4; ++it) {
    gload16(kbase[it], &Ks[0][(wid * 4 + it) * 512]);
    gload16(vbase[it], &Vs[0][(wid * 4 + it) * 512]);
  }
  for (int c = 0; c < nchunks; ++c) {
    __syncthreads();  // chunk c landed; buffer (c+1)&1 free
    if (c + 1 < nchunks) {
      int b = (c + 1) & 1;
#pragma unroll
      for (int it = 0; it < 4; ++it) {
        gload16(kbase[it] + (size_t)(c + 1) * 65536, &Ks[b][(wid * 4 + it) * 512]);
        gload16(vbase[it] + (c + 1) * 64, &Vs[b][(wid * 4 + it) * 512]);
      }
    }
    const unsigned short* Ksc = Ks[c & 1];
    const unsigned short* Vsc = Vs[c & 1];

    // ---- QK^T: S 16x64 per wave ----
    float4_t s[4];
#pragma unroll
    for (int j = 0; j < 4; ++j) {
      float4_t a = (float4_t){0.f, 0.f, 0.f, 0.f};
#pragma unroll
      for (int kb = 0; kb < 4; ++kb) {
        short8_t kf = *(const short8_t*)&Ksc[(j * 16 + l16) * 128 + (((kb * 4 + quad) ^ (l16 & 7)) << 3)];
        a = __builtin_amdgcn_mfma_f32_16x16x32_bf16(qf[kb], kf, a, 0, 0, 0);
      }
      s[j] = a;
    }
    // ---- p = exp(logit - MFIX); causal mask only on diagonal chunk ----
    if (c == tile) {
#pragma unroll
      for (int reg = 0; reg < 4; ++reg) {
        int trow = tbase + reg;
#pragma unroll
        for (int j = 0; j < 4; ++j) {
          float p = __expf(s[j][reg] * SCALE_ - MFIX_);
          s[j][reg] = (c * 64 + j * 16 + l16 <= trow) ? p : 0.f;
        }
      }
    } else {
#pragma unroll
      for (int j = 0; j < 4; ++j)
#pragma unroll
        for (int reg = 0; reg < 4; ++reg)
          s[j][reg] = __expf(s[j][reg] * SCALE_ - MFIX_);
    }
    // write P (C layout) -> per-wave LDS [r][s]
#pragma unroll
    for (int j = 0; j < 4; ++j)
#pragma unroll
      for (int reg = 0; reg < 4; ++reg)
        Ps[wid][(quad * 4 + reg) * 72 + j * 16 + l16] = f2bf(s[j][reg]);
    // ---- PV + row-sum via all-ones MFMA ----
    float4_t pool = (float4_t){0.f, 0.f, 0.f, 0.f};
#pragma unroll
    for (int ks = 0; ks < 2; ++ks) {
      short8_t pf = *(const short8_t*)&Ps[wid][l16 * 72 + ks * 32 + quad * 8];
      pool = __builtin_amdgcn_mfma_f32_16x16x32_bf16(pf, ones, pool, 0, 0, 0);
#pragma unroll
      for (int jt = 0; jt < 8; ++jt) {
        short8_t vf = *(const short8_t*)&Vsc[(jt * 16 + l16) * 64 + (((ks * 4 + quad) ^ (l16 & 7)) << 3)];
        o[jt] = __builtin_amdgcn_mfma_f32_16x16x32_bf16(pf, vf, o[jt], 0, 0, 0);
      }
    }
    int half = c >> 4, cl = c & 15;
#pragma unroll
    for (int reg = 0; reg < 4; ++reg) {
      l_[reg] += pool[reg];
      if (l16 == cl) pacc[half][reg] = pool[reg];
    }
  }
  // epilogue
  float inv[4];
#pragma unroll
  for (int reg = 0; reg < 4; ++reg) inv[reg] = 1.f / l_[reg];
#pragma unroll
  for (int jt = 0; jt < 8; ++jt)
#pragma unroll
    for (int reg = 0; reg < 4; ++reg)
      attnb[(size_t)(tbase + reg) * (H_ * D_) + h * D_ + jt * 16 + l16] =
          f2bf(o[jt][reg] * inv[reg]);
#pragma unroll
  for (int reg = 0; reg < 4; ++reg) {
    int trow = tbase + reg;
    pooled[((size_t)h * T_ + trow) * NB_ + l16] = pacc[0][reg] * inv[reg];
    pooled[((size_t)h * T_ + trow) * NB_ + 16 + l16] = pacc[1][reg] * inv[reg];
  }
}

// ---------- gate loss v2: 8 t per block (half-wave per t), float4 dots ----------
__global__ __launch_bounds__(256) void gate_loss2(const float* __restrict__ gq,
                                                  const float* __restrict__ gk,
                                                  const float* __restrict__ pooled,
                                                  float* __restrict__ klsum) {
  int kv = blockIdx.x;
  int sub = threadIdx.x >> 5;  // 0..7
  int n = threadIdx.x & 31;
  int tloc = blockIdx.y * 8 + sub;
  bool act = tloc < (T_ - START_);
  int t = START_ + (act ? tloc : 0);
  const float4* a = (const float4*)(gq + ((size_t)(t - TG0_) * KV_ + kv) * GH_);
  const float4* b = (const float4*)(gk + (size_t)(n * KV_ + kv) * GH_);
  float dot = 0.f;
#pragma unroll
  for (int d4 = 0; d4 < 32; ++d4) {
    float4 av = a[d4], bv = b[d4];
    dot += av.x * bv.x + av.y * bv.y + av.z * bv.z + av.w * bv.w;
  }
  bool valid = (t / BS_) >= n;
  float score = valid ? dot * SCALE_ : -1e9f;
  float M = score;
#pragma unroll
  for (int o = 16; o > 0; o >>= 1) M = fmaxf(M, __shfl_xor(M, o, 64));
  float e = __expf(score - M);
  float Z = e;
#pragma unroll
  for (int o = 16; o > 0; o >>= 1) Z += __shfl_xor(Z, o, 64);
  float logZ = M + logf(Z);
  float g = 0.f;
  if (valid) {
    float p0 = pooled[((size_t)(kv * G_) * T_ + t) * NB_ + n];
    float p1 = pooled[((size_t)(kv * G_ + 1) * T_ + t) * NB_ + n];
    g = fmaxf(p0, p1);
  }
  float gs = g;
#pragma unroll
  for (int o = 16; o > 0; o >>= 1) gs += __shfl_xor(gs, o, 64);
  float tgt = g / (gs + 1e-9f);
  float kl = (tgt > 0.f) ? tgt * (logf(tgt) - (score - logZ)) : 0.f;
  float ks = kl;
#pragma unroll
  for (int o = 16; o > 0; o >>= 1) ks += __shfl_xor(ks, o, 64);
  if (n == 0 && act) klsum[kv * (T_ - START_) + tloc] = ks;
}

__global__ __launch_bounds__(256) void finalize_loss(const float* __restrict__ klsum,
                                                     float* __restrict__ out) {
  const int n = KV_ * (T_ - START_);
  float s = 0.f;
  for (int i = threadIdx.x; i < n; i += 256) s += klsum[i];
  s = wave_sum(s);
  __shared__ float sh[4];
  if ((threadIdx.x & 63) == 0) sh[threadIdx.x >> 6] = s;
  __syncthreads();
  if (threadIdx.x == 0)
    out[0] = (sh[0] + sh[1] + sh[2] + sh[3]) * (1.f / ((float)(T_ - START_) * NB_));
}

extern "C" void kernel_launch(void* const* d_in, const int* in_sizes, int n_in,
                              void* d_out, int out_size, void* d_ws, size_t ws_size,
                              hipStream_t stream) {
  const float* hs   = (const float*)d_in[0];
  const float* Wq   = (const float*)d_in[1];
  const float* Wk   = (const float*)d_in[2];
  const float* Wv   = (const float*)d_in[3];
  const float* Wo   = (const float*)d_in[4];
  const float* qw   = (const float*)d_in[5];
  const float* kw   = (const float*)d_in[6];
  const float* gwq  = (const float*)d_in[7];
  const float* gwk  = (const float*)d_in[8];
  const float* cosT = (const float*)d_in[9];
  const float* sinT = (const float*)d_in[10];
  const float* cosG = (const float*)d_in[11];
  const float* sinG = (const float*)d_in[12];
  const float* cosB = (const float*)d_in[13];
  const float* sinB = (const float*)d_in[14];
  float* out = (float*)d_out;
  float* ws = (float*)d_ws;
  const size_t MEG = 1048576;

  // ---- workspace layout (float offsets), lifetime-aliased ----
  float*          qkvf     = ws;                                 // [0,8M): [T][4096] fp32
  unsigned short* attnb    = (unsigned short*)ws;                //   alias after qkvf consumed
  float*          pooled   = ws + 2 * MEG;                       //   alias
  float*          klsum    = ws + 3 * MEG;                       //   alias
  unsigned short* WqkvT    = (unsigned short*)(ws + 8 * MEG);    // [8M,12M): 8M ushorts
  unsigned short* qbf      = WqkvT;                              //   alias after qkv gemm
  unsigned short* kbf      = WqkvT + 4 * MEG;
  unsigned short* vt       = WqkvT + 6 * MEG;
  unsigned short* hsb      = (unsigned short*)(ws + 12 * MEG);   // [12M,14M)
  float*          knorm    = ws + 12 * MEG;                      //   alias after qkv gemm
  unsigned short* WoT      = (unsigned short*)(ws + 14 * MEG);   // [14M,16M)
  unsigned short* qpool_bf = (unsigned short*)(ws + 16 * MEG);   // [16M,...)
  float*          gq       = ws + 17 * MEG;
  unsigned short* kblk_bf  = (unsigned short*)(ws + 18 * MEG + 786432);
  float*          gk       = ws + 18 * MEG + 819200;
  unsigned short* gwqT     = (unsigned short*)(ws + 18 * MEG + 851968);
  unsigned short* gwkT     = (unsigned short*)(ws + 18 * MEG + 860160);

  prep_cast<<<7176, 256, 0, stream>>>(hs, Wq, Wk, Wv, Wo, gwq, gwk, hsb, WqkvT, WoT, gwqT, gwkT);
  gemm_bf16_v3<<<dim3(32, 16), 256, 0, stream>>>(hsb, WqkvT, qkvf, 2048, 4096, 2048, 4096);
  norm_rope_fused<<<dim3(T_, 16), 128, 0, stream>>>(qkvf, qw, kw, cosT, sinT, qbf, qpool_bf,
                                                    kbf, knorm);
  castT<<<dim3(16, 32), 256, 0, stream>>>(qkvf + 3072, vt, T_, 1024, 4096);
  kblk_kernel<<<dim3(NB_, KV_), 128, 0, stream>>>(knorm, kblk_bf);
  gemm_bf16_v3<<<dim3(1, 104), 256, 0, stream>>>(qpool_bf, gwqT, gq, 13312, 128, 128, 128);
  gemm_bf16_v3<<<dim3(1, 2), 256, 0, stream>>>(kblk_bf, gwkT, gk, 256, 128, 128, 128);
  rope_g_fused<<<dim3(NB_ + (T_ - TG0_), KV_), 128, 0, stream>>>(gq, gk, cosG, sinG, cosB, sinB);
  attn_mfma<<<dim3(H_, 32), 256, 0, stream>>>(qbf, kbf, vt, attnb, pooled);
  gemm_bf16_v3<<<dim3(16, 16), 256, 0, stream>>>(attnb, WoT, out, 2048, 2048, 2048, 2048);
  gate_loss2<<<dim3(KV_, 205), 256, 0, stream>>>(gq, gk, pooled, klsum);
  finalize_loss<<<1, 256, 0, stream>>>(klsum, out + (size_t)T_ * HID_);
}